// Round 1
// baseline (8996.327 us; speedup 1.0000x reference)
//
#include <hip/hip_runtime.h>
#include <hip/hip_bf16.h>

// Problem constants (fixed by the reference)
#define E_EDGES 200000
#define T_TRIP  2000000
#define N_NODES 20000
#define H_DIM   128
#define INT_DIM 64
#define BAS     8
#define OUT_EMB 256
#define NRAD    6
#define SBF_D   42
#define NB      4

// epilogue flags
#define F_BIAS 1
#define F_SILU 2
#define F_RES  4
#define F_GATE 8

__device__ __forceinline__ float silu_f(float v) { return v / (1.0f + __expf(-v)); }

// ---------------------------------------------------------------------------
// Generic tiled SGEMM: C[M,N] = epi(A[M,K] @ W[K,N])
// epi: (+bias) -> silu -> (*gate from rbf8@Wr2) -> (+res)
// Tiles 64x64, 256 threads, 4x4 per thread. N must be a multiple of 64,
// K a multiple of 16. M arbitrary (bounds-checked).
// ---------------------------------------------------------------------------
__global__ __launch_bounds__(256) void sgemm_epi(
    const float* __restrict__ A, const float* __restrict__ W,
    const float* __restrict__ bias, const float* __restrict__ res,
    const float* __restrict__ rbf8v, const float* __restrict__ Wr2,
    float* __restrict__ C, int M, int N, int K, int flags)
{
    __shared__ float As[16][68];  // [k][m], padded: 68*4B=272B rows keep 16B align
    __shared__ float Ws[16][68];  // [k][n]

    const int bm = blockIdx.y * 64;
    const int bn = blockIdx.x * 64;
    const int tid = threadIdx.x;
    const int tx = tid & 15;       // col group
    const int ty = tid >> 4;       // row group

    float acc[4][4] = {};

    for (int k0 = 0; k0 < K; k0 += 16) {
        // A tile: 64 rows x 16 k. Each thread loads one float4.
        {
            int r  = tid >> 2;
            int kk = (tid & 3) * 4;
            int row = bm + r;
            float4 v = make_float4(0.f, 0.f, 0.f, 0.f);
            if (row < M)
                v = *reinterpret_cast<const float4*>(&A[(size_t)row * K + k0 + kk]);
            As[kk + 0][r] = v.x; As[kk + 1][r] = v.y;
            As[kk + 2][r] = v.z; As[kk + 3][r] = v.w;
        }
        // W tile: 16 k x 64 n. Each thread loads one float4.
        {
            int kk = tid >> 4;
            int c  = (tid & 15) * 4;
            float4 v = *reinterpret_cast<const float4*>(&W[(size_t)(k0 + kk) * N + bn + c]);
            Ws[kk][c + 0] = v.x; Ws[kk][c + 1] = v.y;
            Ws[kk][c + 2] = v.z; Ws[kk][c + 3] = v.w;
        }
        __syncthreads();
        #pragma unroll
        for (int k = 0; k < 16; ++k) {
            float4 a4 = *reinterpret_cast<const float4*>(&As[k][ty * 4]);
            float4 w4 = *reinterpret_cast<const float4*>(&Ws[k][tx * 4]);
            float a[4] = {a4.x, a4.y, a4.z, a4.w};
            float w[4] = {w4.x, w4.y, w4.z, w4.w};
            #pragma unroll
            for (int i = 0; i < 4; ++i)
                #pragma unroll
                for (int j = 0; j < 4; ++j)
                    acc[i][j] = fmaf(a[i], w[j], acc[i][j]);
        }
        __syncthreads();
    }

    const int row0 = bm + ty * 4;
    const int col0 = bn + tx * 4;
    #pragma unroll
    for (int i = 0; i < 4; ++i) {
        int row = row0 + i;
        if (row >= M) break;
        #pragma unroll
        for (int j = 0; j < 4; ++j) {
            int col = col0 + j;
            float v = acc[i][j];
            if (flags & F_BIAS) v += bias[col];
            if (flags & F_SILU) v = silu_f(v);
            if (flags & F_GATE) {
                float g = 0.f;
                #pragma unroll
                for (int jj = 0; jj < 8; ++jj)
                    g = fmaf(rbf8v[(size_t)row * 8 + jj], Wr2[jj * N + col], g);
                v *= g;
            }
            if (flags & F_RES) v += res[(size_t)row * N + col];
            C[(size_t)row * N + col] = v;
        }
    }
}

// rbf8[e][j] = sum_k rbf[e][k] * W1[k][j]   (W1 = W_rbf1[b], [6,8])
__global__ __launch_bounds__(256) void rbf8_kernel(
    const float* __restrict__ rbf, const float* __restrict__ W1,
    float* __restrict__ r8, int Ecount)
{
    int e = blockIdx.x * blockDim.x + threadIdx.x;
    if (e >= Ecount) return;
    float rv[NRAD];
    #pragma unroll
    for (int k = 0; k < NRAD; ++k) rv[k] = rbf[(size_t)e * NRAD + k];
    float acc[BAS] = {};
    #pragma unroll
    for (int k = 0; k < NRAD; ++k)
        #pragma unroll
        for (int j = 0; j < BAS; ++j)
            acc[j] = fmaf(rv[k], W1[k * BAS + j], acc[j]);
    float4* o = reinterpret_cast<float4*>(&r8[(size_t)e * BAS]);
    o[0] = make_float4(acc[0], acc[1], acc[2], acc[3]);
    o[1] = make_float4(acc[4], acc[5], acc[6], acc[7]);
}

// sbf8[t][j] = sum_k sbf[t][k] * W1[k][j]   (W1 = W_sbf1[b], [42,8])
__global__ __launch_bounds__(256) void sbf8_kernel(
    const float* __restrict__ sbf, const float* __restrict__ W1,
    float* __restrict__ s8, int Tcount)
{
    int t = blockIdx.x * blockDim.x + threadIdx.x;
    if (t >= Tcount) return;
    float acc[BAS] = {};
    const float* srow = &sbf[(size_t)t * SBF_D];
    for (int k = 0; k < SBF_D; ++k) {
        float sv = srow[k];
        #pragma unroll
        for (int j = 0; j < BAS; ++j)
            acc[j] = fmaf(sv, W1[k * BAS + j], acc[j]);
    }
    float4* o = reinterpret_cast<float4*>(&s8[(size_t)t * BAS]);
    o[0] = make_float4(acc[0], acc[1], acc[2], acc[3]);
    o[1] = make_float4(acc[4], acc[5], acc[6], acc[7]);
}

// For each triplet t (one wave each): lane c in [0,64):
//   sbf_t = dot(sbf8[t][:], W_sbf2[:,c]);  m = xkj[idx_kj[t]][c] * sbf_t
//   agg[idx_ji[t]][c] += m  (atomic)
__global__ __launch_bounds__(256) void triplet_scatter(
    const float* __restrict__ s8, const float* __restrict__ Wsb2,
    const float* __restrict__ xkj,
    const int* __restrict__ idx_kj, const int* __restrict__ idx_ji,
    float* __restrict__ agg, int Tcount)
{
    const int lane = threadIdx.x & 63;
    int wid = (blockIdx.x * blockDim.x + threadIdx.x) >> 6;
    const int nw = (gridDim.x * blockDim.x) >> 6;
    float w2[BAS];
    #pragma unroll
    for (int j = 0; j < BAS; ++j) w2[j] = Wsb2[j * INT_DIM + lane];
    for (int t = wid; t < Tcount; t += nw) {
        int ekj = idx_kj[t];
        int eji = idx_ji[t];
        const float* srow = &s8[(size_t)t * BAS];
        float s = 0.f;
        #pragma unroll
        for (int j = 0; j < BAS; ++j) s = fmaf(srow[j], w2[j], s);
        float m = xkj[(size_t)ekj * INT_DIM + lane] * s;
        unsafeAtomicAdd(&agg[(size_t)eji * INT_DIM + lane], m);
    }
}

// Output-block edge scatter: tN[idx_i[e]][h] += (rbf[e] @ Wo_rbf)[h] * x[e][h]
__global__ __launch_bounds__(256) void out_edge_scatter(
    const float* __restrict__ rbf, const float* __restrict__ Wor,
    const float* __restrict__ x, const int* __restrict__ idx_i,
    float* __restrict__ tN, int Ecount)
{
    __shared__ float Wr[NRAD * H_DIM];
    for (int i = threadIdx.x; i < NRAD * H_DIM; i += blockDim.x) Wr[i] = Wor[i];
    __syncthreads();
    const int lane = threadIdx.x & 63;
    int wid = (blockIdx.x * blockDim.x + threadIdx.x) >> 6;
    const int nw = (gridDim.x * blockDim.x) >> 6;
    for (int e = wid; e < Ecount; e += nw) {
        int ni = idx_i[e];
        float r[NRAD];
        #pragma unroll
        for (int k = 0; k < NRAD; ++k) r[k] = rbf[(size_t)e * NRAD + k];
        #pragma unroll
        for (int h0 = 0; h0 < 2; ++h0) {
            int h = lane + h0 * 64;
            float v = 0.f;
            #pragma unroll
            for (int k = 0; k < NRAD; ++k) v = fmaf(r[k], Wr[k * H_DIM + h], v);
            v *= x[(size_t)e * H_DIM + h];
            unsafeAtomicAdd(&tN[(size_t)ni * H_DIM + h], v);
        }
    }
}

// P[n] += dot(Tb[n][:256], Wo[:256])  — one wave per node
__global__ __launch_bounds__(256) void out_final(
    const float* __restrict__ Tb, const float* __restrict__ Wo,
    float* __restrict__ P, int Nn)
{
    const int lane = threadIdx.x & 63;
    int node = (blockIdx.x * blockDim.x + threadIdx.x) >> 6;
    if (node >= Nn) return;
    float s = 0.f;
    #pragma unroll
    for (int i = 0; i < 4; ++i) {
        int c = lane + i * 64;
        s = fmaf(Tb[(size_t)node * OUT_EMB + c], Wo[c], s);
    }
    #pragma unroll
    for (int o = 32; o > 0; o >>= 1) s += __shfl_xor(s, o);
    if (lane == 0) P[node] += s;
}

// ---------------------------------------------------------------------------
extern "C" void kernel_launch(void* const* d_in, const int* in_sizes, int n_in,
                              void* d_out, int out_size, void* d_ws, size_t ws_size,
                              hipStream_t stream)
{
    const float* x_in    = (const float*)d_in[0];
    const float* rbf     = (const float*)d_in[1];
    const float* sbf     = (const float*)d_in[2];
    const float* W_rbf1  = (const float*)d_in[3];
    const float* W_rbf2  = (const float*)d_in[4];
    const float* W_sbf1  = (const float*)d_in[5];
    const float* W_sbf2  = (const float*)d_in[6];
    const float* W_kj    = (const float*)d_in[7];
    const float* b_kj    = (const float*)d_in[8];
    const float* W_ji    = (const float*)d_in[9];
    const float* b_ji    = (const float*)d_in[10];
    const float* W_down  = (const float*)d_in[11];
    const float* W_up    = (const float*)d_in[12];
    const float* Wb      = (const float*)d_in[13];
    const float* bb      = (const float*)d_in[14];
    const float* Wa      = (const float*)d_in[15];
    const float* ba      = (const float*)d_in[16];
    const float* W_lin   = (const float*)d_in[17];
    const float* b_lin   = (const float*)d_in[18];
    const float* Wo_rbf  = (const float*)d_in[19];
    const float* Wo_up   = (const float*)d_in[20];
    const float* bo_up   = (const float*)d_in[21];
    const float* Wo_lins = (const float*)d_in[22];
    const float* bo_lins = (const float*)d_in[23];
    const float* Wo_out  = (const float*)d_in[24];
    const int*   idx_kj  = (const int*)d_in[25];
    const int*   idx_ji  = (const int*)d_in[26];
    const int*   idx_i   = (const int*)d_in[27];

    // workspace carve-up
    char* ws = (char*)d_ws;
    size_t off = 0;
    auto alloc = [&](size_t bytes) -> float* {
        float* p = (float*)(ws + off);
        off += (bytes + 255) & ~(size_t)255;
        return p;
    };
    float* XA   = alloc((size_t)E_EDGES * H_DIM * 4);
    float* XB   = alloc((size_t)E_EDGES * H_DIM * 4);
    float* E1   = alloc((size_t)E_EDGES * H_DIM * 4);
    float* E2   = alloc((size_t)E_EDGES * H_DIM * 4);
    float* C1   = alloc((size_t)E_EDGES * INT_DIM * 4);
    float* C2   = alloc((size_t)E_EDGES * INT_DIM * 4);
    float* R8   = alloc((size_t)E_EDGES * BAS * 4);
    float* S8   = alloc((size_t)T_TRIP * BAS * 4);
    float* TN   = alloc((size_t)N_NODES * H_DIM * 4);
    float* T1   = alloc((size_t)N_NODES * OUT_EMB * 4);
    float* T2   = alloc((size_t)N_NODES * OUT_EMB * 4);
    (void)ws_size;

    auto gemm = [&](const float* A, const float* W, const float* bias,
                    const float* res, const float* r8, const float* Wr2,
                    float* C, int M, int N, int K, int flags) {
        dim3 g(N / 64, (M + 63) / 64), b(256);
        hipLaunchKernelGGL(sgemm_epi, g, b, 0, stream,
                           A, W, bias, res, r8, Wr2, C, M, N, K, flags);
    };

    float* P = (float*)d_out;
    hipMemsetAsync(P, 0, (size_t)N_NODES * sizeof(float), stream);

    auto out_block = [&](int ob, const float* xcur) {
        hipMemsetAsync(TN, 0, (size_t)N_NODES * H_DIM * 4, stream);
        hipLaunchKernelGGL(out_edge_scatter, dim3(1024), dim3(256), 0, stream,
                           rbf, Wo_rbf + (size_t)ob * NRAD * H_DIM, xcur, idx_i, TN, E_EDGES);
        gemm(TN, Wo_up + (size_t)ob * H_DIM * OUT_EMB, bo_up + (size_t)ob * OUT_EMB,
             nullptr, nullptr, nullptr, T1, N_NODES, OUT_EMB, H_DIM, F_BIAS);
        gemm(T1, Wo_lins + (size_t)(ob * 3 + 0) * OUT_EMB * OUT_EMB,
             bo_lins + (size_t)(ob * 3 + 0) * OUT_EMB,
             nullptr, nullptr, nullptr, T2, N_NODES, OUT_EMB, OUT_EMB, F_BIAS | F_SILU);
        gemm(T2, Wo_lins + (size_t)(ob * 3 + 1) * OUT_EMB * OUT_EMB,
             bo_lins + (size_t)(ob * 3 + 1) * OUT_EMB,
             nullptr, nullptr, nullptr, T1, N_NODES, OUT_EMB, OUT_EMB, F_BIAS | F_SILU);
        gemm(T1, Wo_lins + (size_t)(ob * 3 + 2) * OUT_EMB * OUT_EMB,
             bo_lins + (size_t)(ob * 3 + 2) * OUT_EMB,
             nullptr, nullptr, nullptr, T2, N_NODES, OUT_EMB, OUT_EMB, F_BIAS | F_SILU);
        hipLaunchKernelGGL(out_final, dim3((N_NODES * 64 + 255) / 256), dim3(256), 0, stream,
                           T2, Wo_out + (size_t)ob * OUT_EMB, P, N_NODES);
    };

    out_block(0, x_in);

    const float* xcur = x_in;
    for (int b = 0; b < NB; ++b) {
        float* xnext = (b % 2 == 0) ? XB : XA;
        // per-block rbf embedding (depends on W_rbf1[b])
        hipLaunchKernelGGL(rbf8_kernel, dim3((E_EDGES + 255) / 256), dim3(256), 0, stream,
                           rbf, W_rbf1 + (size_t)b * NRAD * BAS, R8, E_EDGES);
        // x_ji = silu(x @ W_ji + b_ji)
        gemm(xcur, W_ji + (size_t)b * H_DIM * H_DIM, b_ji + (size_t)b * H_DIM,
             nullptr, nullptr, nullptr, E1, E_EDGES, H_DIM, H_DIM, F_BIAS | F_SILU);
        // x_kj_g = silu(x @ W_kj + b_kj) * (rbf8 @ W_rbf2)
        gemm(xcur, W_kj + (size_t)b * H_DIM * H_DIM, b_kj + (size_t)b * H_DIM,
             nullptr, R8, W_rbf2 + (size_t)b * BAS * H_DIM,
             E2, E_EDGES, H_DIM, H_DIM, F_BIAS | F_SILU | F_GATE);
        // x_kj_d = silu(x_kj_g @ W_down)
        gemm(E2, W_down + (size_t)b * H_DIM * INT_DIM, nullptr,
             nullptr, nullptr, nullptr, C1, E_EDGES, INT_DIM, H_DIM, F_SILU);
        // sbf basis (depends on W_sbf1[b])
        hipLaunchKernelGGL(sbf8_kernel, dim3((T_TRIP + 255) / 256), dim3(256), 0, stream,
                           sbf, W_sbf1 + (size_t)b * SBF_D * BAS, S8, T_TRIP);
        // triplet gather-scale-scatter
        hipMemsetAsync(C2, 0, (size_t)E_EDGES * INT_DIM * 4, stream);
        hipLaunchKernelGGL(triplet_scatter, dim3(4096), dim3(256), 0, stream,
                           S8, W_sbf2 + (size_t)b * BAS * INT_DIM, C1, idx_kj, idx_ji, C2, T_TRIP);
        // h = x_ji + silu(agg @ W_up)
        gemm(C2, W_up + (size_t)b * INT_DIM * H_DIM, nullptr,
             E1, nullptr, nullptr, E1, E_EDGES, H_DIM, INT_DIM, F_SILU | F_RES);
        // before-skip residual layer
        gemm(E1, Wb + (size_t)(b * 2 + 0) * H_DIM * H_DIM, bb + (size_t)(b * 2 + 0) * H_DIM,
             nullptr, nullptr, nullptr, E2, E_EDGES, H_DIM, H_DIM, F_BIAS | F_SILU);
        gemm(E2, Wb + (size_t)(b * 2 + 1) * H_DIM * H_DIM, bb + (size_t)(b * 2 + 1) * H_DIM,
             E1, nullptr, nullptr, E1, E_EDGES, H_DIM, H_DIM, F_BIAS | F_SILU | F_RES);
        // skip: x_next = silu(h @ W_lin + b_lin) + x
        gemm(E1, W_lin + (size_t)b * H_DIM * H_DIM, b_lin + (size_t)b * H_DIM,
             xcur, nullptr, nullptr, xnext, E_EDGES, H_DIM, H_DIM, F_BIAS | F_SILU | F_RES);
        // after-skip residual layers
        for (int l = 0; l < 2; ++l) {
            gemm(xnext, Wa + (size_t)(b * 4 + 2 * l) * H_DIM * H_DIM,
                 ba + (size_t)(b * 4 + 2 * l) * H_DIM,
                 nullptr, nullptr, nullptr, E2, E_EDGES, H_DIM, H_DIM, F_BIAS | F_SILU);
            gemm(E2, Wa + (size_t)(b * 4 + 2 * l + 1) * H_DIM * H_DIM,
                 ba + (size_t)(b * 4 + 2 * l + 1) * H_DIM,
                 xnext, nullptr, nullptr, xnext, E_EDGES, H_DIM, H_DIM, F_BIAS | F_SILU | F_RES);
        }
        xcur = xnext;
        out_block(b + 1, xcur);
    }
}

// Round 2
// 7616.836 us; speedup vs baseline: 1.1811x; 1.1811x over previous
//
#include <hip/hip_runtime.h>
#include <hip/hip_bf16.h>

// Problem constants (fixed by the reference)
#define E_EDGES 200000
#define T_TRIP  2000000
#define N_NODES 20000
#define H_DIM   128
#define INT_DIM 64
#define BAS     8
#define OUT_EMB 256
#define NRAD    6
#define SBF_D   42
#define NB      4

// epilogue flags
#define F_BIAS 1
#define F_SILU 2
#define F_RES  4
#define F_GATE 8

typedef __attribute__((ext_vector_type(8))) __bf16 bf16x8;
typedef __attribute__((ext_vector_type(4))) float f32x4;

__device__ __forceinline__ float silu_f(float v) { return v / (1.0f + __expf(-v)); }

__device__ __forceinline__ unsigned short f2bf(float f) {
    unsigned int u = __float_as_uint(f);
    u += 0x7FFF + ((u >> 16) & 1);   // RNE
    return (unsigned short)(u >> 16);
}
__device__ __forceinline__ float bf2f(unsigned short h) {
    return __uint_as_float(((unsigned int)h) << 16);
}

// ---------------------------------------------------------------------------
// Weight prep: src [cnt][K][N] f32 row-major -> hi/lo [cnt][N][K] split-bf16
// ---------------------------------------------------------------------------
__global__ __launch_bounds__(256) void wprep(
    const float* __restrict__ src, unsigned short* __restrict__ hi,
    unsigned short* __restrict__ lo, int K, int N)
{
    int e = blockIdx.x * 256 + threadIdx.x;
    int total = K * N;
    if (e >= total) return;
    size_t base = (size_t)blockIdx.y * total;
    float a = src[base + e];
    int k = e / N, n = e - k * N;
    unsigned short h = f2bf(a);
    unsigned short l = f2bf(a - bf2f(h));
    hi[base + (size_t)n * K + k] = h;
    lo[base + (size_t)n * K + k] = l;
}

// ---------------------------------------------------------------------------
// Split-bf16 MFMA GEMM: C[M,N] = epi(A[M,K] @ W[K,N]), W pre-split as [N][K].
// Block tile 128(M) x 64(N), 256 threads = 4 waves in 2x2, wave tile 64x32.
// A fp32 staged to LDS as split-bf16 with XOR swizzle; B read direct (L2).
// epi: (+bias) -> silu -> (*gate rbf8@Wr2) -> (+res)
// ---------------------------------------------------------------------------
__global__ __launch_bounds__(256) void mfma_gemm(
    const float* __restrict__ A,
    const unsigned short* __restrict__ Bhi, const unsigned short* __restrict__ Blo,
    const float* __restrict__ bias, const float* __restrict__ res,
    const float* __restrict__ rbf8v, const float* __restrict__ Wr2,
    float* __restrict__ C, int M, int N, int K, int flags)
{
    __shared__ unsigned short AsH[128 * 32];
    __shared__ unsigned short AsL[128 * 32];

    const int tid  = threadIdx.x;
    const int lane = tid & 63;
    const int w    = tid >> 6;
    const int wm   = w >> 1, wn = w & 1;
    const int bm   = blockIdx.y * 128;
    const int bn   = blockIdx.x * 64;
    const int l15  = lane & 15;
    const int khalf = (lane >> 4) * 8;

    // A staging coords: each thread loads 16 consecutive floats (half a row)
    const int sr = tid >> 1;
    const int sc = (tid & 1) * 16;
    int grow = bm + sr; if (grow >= M) grow = M - 1;
    const float* gA = &A[(size_t)grow * K + sc];

    int bcol[2];
    #pragma unroll
    for (int n = 0; n < 2; ++n) bcol[n] = bn + wn * 32 + n * 16 + l15;

    f32x4 acc[4][2] = {};

    for (int k0 = 0; k0 < K; k0 += 32) {
        __syncthreads();
        // ---- stage A tile [128][32] fp32 -> split bf16 in LDS (swizzled)
        {
            const float* p = gA + k0;
            float4 f0 = *reinterpret_cast<const float4*>(p);
            float4 f1 = *reinterpret_cast<const float4*>(p + 4);
            float4 f2 = *reinterpret_cast<const float4*>(p + 8);
            float4 f3 = *reinterpret_cast<const float4*>(p + 12);
            float vv[16] = {f0.x,f0.y,f0.z,f0.w, f1.x,f1.y,f1.z,f1.w,
                            f2.x,f2.y,f2.z,f2.w, f3.x,f3.y,f3.z,f3.w};
            const int swz = (sr & 7) << 4;
            #pragma unroll
            for (int q = 0; q < 4; ++q) {
                unsigned short h[4], l[4];
                #pragma unroll
                for (int j = 0; j < 4; ++j) {
                    float a = vv[q * 4 + j];
                    h[j] = f2bf(a);
                    l[j] = f2bf(a - bf2f(h[j]));
                }
                int off = (sr * 64 + (sc / 4 + q) * 8) ^ swz;
                *reinterpret_cast<ushort4*>((char*)AsH + off) = make_ushort4(h[0], h[1], h[2], h[3]);
                *reinterpret_cast<ushort4*>((char*)AsL + off) = make_ushort4(l[0], l[1], l[2], l[3]);
            }
        }
        __syncthreads();

        // ---- B fragments direct from global (L2-resident, [N][K] layout)
        bf16x8 bh[2], bl[2];
        #pragma unroll
        for (int n = 0; n < 2; ++n) {
            size_t bo = (size_t)bcol[n] * K + k0 + khalf;
            bh[n] = *reinterpret_cast<const bf16x8*>(Bhi + bo);
            bl[n] = *reinterpret_cast<const bf16x8*>(Blo + bo);
        }

        // ---- A fragments from LDS + 3-term split MFMA
        #pragma unroll
        for (int m = 0; m < 4; ++m) {
            int ri  = wm * 64 + m * 16 + l15;
            int off = (ri * 64 + khalf * 2) ^ ((ri & 7) << 4);
            bf16x8 ah = *reinterpret_cast<const bf16x8*>((const char*)AsH + off);
            bf16x8 al = *reinterpret_cast<const bf16x8*>((const char*)AsL + off);
            #pragma unroll
            for (int n = 0; n < 2; ++n) {
                acc[m][n] = __builtin_amdgcn_mfma_f32_16x16x32_bf16(ah, bh[n], acc[m][n], 0, 0, 0);
                acc[m][n] = __builtin_amdgcn_mfma_f32_16x16x32_bf16(al, bh[n], acc[m][n], 0, 0, 0);
                acc[m][n] = __builtin_amdgcn_mfma_f32_16x16x32_bf16(ah, bl[n], acc[m][n], 0, 0, 0);
            }
        }
    }

    // ---- epilogue: C/D layout col=lane&15, row=(lane>>4)*4+reg
    const int r4 = (lane >> 4) * 4;
    #pragma unroll
    for (int m = 0; m < 4; ++m) {
        #pragma unroll
        for (int r = 0; r < 4; ++r) {
            int row = bm + wm * 64 + m * 16 + r4 + r;
            if (row >= M) continue;
            #pragma unroll
            for (int n = 0; n < 2; ++n) {
                int col = bn + wn * 32 + n * 16 + l15;
                float v = acc[m][n][r];
                if (flags & F_BIAS) v += bias[col];
                if (flags & F_SILU) v = silu_f(v);
                if (flags & F_GATE) {
                    float g = 0.f;
                    #pragma unroll
                    for (int j = 0; j < 8; ++j)
                        g = fmaf(rbf8v[(size_t)row * 8 + j], Wr2[j * N + col], g);
                    v *= g;
                }
                if (flags & F_RES) v += res[(size_t)row * N + col];
                C[(size_t)row * N + col] = v;
            }
        }
    }
}

// rbf8[e][j] = rbf[e] @ W_rbf1[b]   [E,8]
__global__ __launch_bounds__(256) void rbf8_kernel(
    const float* __restrict__ rbf, const float* __restrict__ W1,
    float* __restrict__ r8, int Ecount)
{
    int e = blockIdx.x * blockDim.x + threadIdx.x;
    if (e >= Ecount) return;
    float rv[NRAD];
    #pragma unroll
    for (int k = 0; k < NRAD; ++k) rv[k] = rbf[(size_t)e * NRAD + k];
    float acc[BAS] = {};
    #pragma unroll
    for (int k = 0; k < NRAD; ++k)
        #pragma unroll
        for (int j = 0; j < BAS; ++j)
            acc[j] = fmaf(rv[k], W1[k * BAS + j], acc[j]);
    float4* o = reinterpret_cast<float4*>(&r8[(size_t)e * BAS]);
    o[0] = make_float4(acc[0], acc[1], acc[2], acc[3]);
    o[1] = make_float4(acc[4], acc[5], acc[6], acc[7]);
}

// sbf8[t][j] = sbf[t] @ W_sbf1[b]   [T,8]
__global__ __launch_bounds__(256) void sbf8_kernel(
    const float* __restrict__ sbf, const float* __restrict__ W1,
    float* __restrict__ s8, int Tcount)
{
    int t = blockIdx.x * blockDim.x + threadIdx.x;
    if (t >= Tcount) return;
    float acc[BAS] = {};
    const float* srow = &sbf[(size_t)t * SBF_D];
    for (int k = 0; k < SBF_D; ++k) {
        float sv = srow[k];
        #pragma unroll
        for (int j = 0; j < BAS; ++j)
            acc[j] = fmaf(sv, W1[k * BAS + j], acc[j]);
    }
    float4* o = reinterpret_cast<float4*>(&s8[(size_t)t * BAS]);
    o[0] = make_float4(acc[0], acc[1], acc[2], acc[3]);
    o[1] = make_float4(acc[4], acc[5], acc[6], acc[7]);
}

// triplet gather-scale-scatter, one wave per triplet row
__global__ __launch_bounds__(256) void triplet_scatter(
    const float* __restrict__ s8, const float* __restrict__ Wsb2,
    const float* __restrict__ xkj,
    const int* __restrict__ idx_kj, const int* __restrict__ idx_ji,
    float* __restrict__ agg, int Tcount)
{
    const int lane = threadIdx.x & 63;
    int wid = (blockIdx.x * blockDim.x + threadIdx.x) >> 6;
    const int nw = (gridDim.x * blockDim.x) >> 6;
    float w2[BAS];
    #pragma unroll
    for (int j = 0; j < BAS; ++j) w2[j] = Wsb2[j * INT_DIM + lane];
    for (int t = wid; t < Tcount; t += nw) {
        int ekj = idx_kj[t];
        int eji = idx_ji[t];
        const float* srow = &s8[(size_t)t * BAS];
        float s = 0.f;
        #pragma unroll
        for (int j = 0; j < BAS; ++j) s = fmaf(srow[j], w2[j], s);
        float m = xkj[(size_t)ekj * INT_DIM + lane] * s;
        unsafeAtomicAdd(&agg[(size_t)eji * INT_DIM + lane], m);
    }
}

// Output-block edge scatter: tN[idx_i[e]][h] += (rbf[e] @ Wo_rbf)[h] * x[e][h]
__global__ __launch_bounds__(256) void out_edge_scatter(
    const float* __restrict__ rbf, const float* __restrict__ Wor,
    const float* __restrict__ x, const int* __restrict__ idx_i,
    float* __restrict__ tN, int Ecount)
{
    __shared__ float Wr[NRAD * H_DIM];
    for (int i = threadIdx.x; i < NRAD * H_DIM; i += blockDim.x) Wr[i] = Wor[i];
    __syncthreads();
    const int lane = threadIdx.x & 63;
    int wid = (blockIdx.x * blockDim.x + threadIdx.x) >> 6;
    const int nw = (gridDim.x * blockDim.x) >> 6;
    for (int e = wid; e < Ecount; e += nw) {
        int ni = idx_i[e];
        float r[NRAD];
        #pragma unroll
        for (int k = 0; k < NRAD; ++k) r[k] = rbf[(size_t)e * NRAD + k];
        #pragma unroll
        for (int h0 = 0; h0 < 2; ++h0) {
            int h = lane + h0 * 64;
            float v = 0.f;
            #pragma unroll
            for (int k = 0; k < NRAD; ++k) v = fmaf(r[k], Wr[k * H_DIM + h], v);
            v *= x[(size_t)e * H_DIM + h];
            unsafeAtomicAdd(&tN[(size_t)ni * H_DIM + h], v);
        }
    }
}

// P[n] += dot(Tb[n][:256], Wo[:256]) — one wave per node
__global__ __launch_bounds__(256) void out_final(
    const float* __restrict__ Tb, const float* __restrict__ Wo,
    float* __restrict__ P, int Nn)
{
    const int lane = threadIdx.x & 63;
    int node = (blockIdx.x * blockDim.x + threadIdx.x) >> 6;
    if (node >= Nn) return;
    float s = 0.f;
    #pragma unroll
    for (int i = 0; i < 4; ++i) {
        int c = lane + i * 64;
        s = fmaf(Tb[(size_t)node * OUT_EMB + c], Wo[c], s);
    }
    #pragma unroll
    for (int o = 32; o > 0; o >>= 1) s += __shfl_xor(s, o);
    if (lane == 0) P[node] += s;
}

// ---------------------------------------------------------------------------
extern "C" void kernel_launch(void* const* d_in, const int* in_sizes, int n_in,
                              void* d_out, int out_size, void* d_ws, size_t ws_size,
                              hipStream_t stream)
{
    const float* x_in    = (const float*)d_in[0];
    const float* rbf     = (const float*)d_in[1];
    const float* sbf     = (const float*)d_in[2];
    const float* W_rbf1  = (const float*)d_in[3];
    const float* W_rbf2  = (const float*)d_in[4];
    const float* W_sbf1  = (const float*)d_in[5];
    const float* W_sbf2  = (const float*)d_in[6];
    const float* W_kj    = (const float*)d_in[7];
    const float* b_kj    = (const float*)d_in[8];
    const float* W_ji    = (const float*)d_in[9];
    const float* b_ji    = (const float*)d_in[10];
    const float* W_down  = (const float*)d_in[11];
    const float* W_up    = (const float*)d_in[12];
    const float* Wb      = (const float*)d_in[13];
    const float* bb      = (const float*)d_in[14];
    const float* Wa      = (const float*)d_in[15];
    const float* ba      = (const float*)d_in[16];
    const float* W_lin   = (const float*)d_in[17];
    const float* b_lin   = (const float*)d_in[18];
    const float* Wo_rbf  = (const float*)d_in[19];
    const float* Wo_up   = (const float*)d_in[20];
    const float* bo_up   = (const float*)d_in[21];
    const float* Wo_lins = (const float*)d_in[22];
    const float* bo_lins = (const float*)d_in[23];
    const float* Wo_out  = (const float*)d_in[24];
    const int*   idx_kj  = (const int*)d_in[25];
    const int*   idx_ji  = (const int*)d_in[26];
    const int*   idx_i   = (const int*)d_in[27];

    // workspace carve-up
    char* ws = (char*)d_ws;
    size_t off = 0;
    auto alloc = [&](size_t bytes) -> void* {
        void* p = (void*)(ws + off);
        off += (bytes + 255) & ~(size_t)255;
        return p;
    };
    float* XA = (float*)alloc((size_t)E_EDGES * H_DIM * 4);
    float* XB = (float*)alloc((size_t)E_EDGES * H_DIM * 4);
    float* E1 = (float*)alloc((size_t)E_EDGES * H_DIM * 4);
    float* E2 = (float*)alloc((size_t)E_EDGES * H_DIM * 4);
    float* C1 = (float*)alloc((size_t)E_EDGES * INT_DIM * 4);
    float* C2 = (float*)alloc((size_t)E_EDGES * INT_DIM * 4);
    float* R8 = (float*)alloc((size_t)E_EDGES * BAS * 4);
    float* S8 = (float*)alloc((size_t)T_TRIP * BAS * 4);
    float* TN = (float*)alloc((size_t)N_NODES * H_DIM * 4);
    float* T1 = (float*)alloc((size_t)N_NODES * OUT_EMB * 4);
    float* T2 = (float*)alloc((size_t)N_NODES * OUT_EMB * 4);
    // split-bf16 transposed weights
    typedef unsigned short u16;
    u16* HKJ = (u16*)alloc(4  * 16384 * 2); u16* LKJ = (u16*)alloc(4  * 16384 * 2);
    u16* HJI = (u16*)alloc(4  * 16384 * 2); u16* LJI = (u16*)alloc(4  * 16384 * 2);
    u16* HDN = (u16*)alloc(4  * 8192  * 2); u16* LDN = (u16*)alloc(4  * 8192  * 2);
    u16* HUP = (u16*)alloc(4  * 8192  * 2); u16* LUP = (u16*)alloc(4  * 8192  * 2);
    u16* HWB = (u16*)alloc(8  * 16384 * 2); u16* LWB = (u16*)alloc(8  * 16384 * 2);
    u16* HWA = (u16*)alloc(16 * 16384 * 2); u16* LWA = (u16*)alloc(16 * 16384 * 2);
    u16* HLN = (u16*)alloc(4  * 16384 * 2); u16* LLN = (u16*)alloc(4  * 16384 * 2);
    u16* HOU = (u16*)alloc(5  * 32768 * 2); u16* LOU = (u16*)alloc(5  * 32768 * 2);
    u16* HOL = (u16*)alloc(15 * 65536 * 2); u16* LOL = (u16*)alloc(15 * 65536 * 2);
    (void)ws_size;

    auto prep = [&](const float* src, u16* hi, u16* lo, int K, int N, int cnt) {
        dim3 g((K * N + 255) / 256, cnt);
        hipLaunchKernelGGL(wprep, g, dim3(256), 0, stream, src, hi, lo, K, N);
    };
    prep(W_kj,    HKJ, LKJ, 128, 128, 4);
    prep(W_ji,    HJI, LJI, 128, 128, 4);
    prep(W_down,  HDN, LDN, 128, 64,  4);
    prep(W_up,    HUP, LUP, 64,  128, 4);
    prep(Wb,      HWB, LWB, 128, 128, 8);
    prep(Wa,      HWA, LWA, 128, 128, 16);
    prep(W_lin,   HLN, LLN, 128, 128, 4);
    prep(Wo_up,   HOU, LOU, 128, 256, 5);
    prep(Wo_lins, HOL, LOL, 256, 256, 15);

    auto gemm = [&](const float* A, const u16* Bh, const u16* Bl, const float* bias,
                    const float* res, const float* r8, const float* Wr2f,
                    float* C, int M, int N, int K, int flags) {
        dim3 g(N / 64, (M + 127) / 128), b(256);
        hipLaunchKernelGGL(mfma_gemm, g, b, 0, stream,
                           A, Bh, Bl, bias, res, r8, Wr2f, C, M, N, K, flags);
    };

    float* P = (float*)d_out;
    hipMemsetAsync(P, 0, (size_t)N_NODES * sizeof(float), stream);

    auto out_block = [&](int ob, const float* xcur) {
        hipMemsetAsync(TN, 0, (size_t)N_NODES * H_DIM * 4, stream);
        hipLaunchKernelGGL(out_edge_scatter, dim3(1024), dim3(256), 0, stream,
                           rbf, Wo_rbf + (size_t)ob * NRAD * H_DIM, xcur, idx_i, TN, E_EDGES);
        gemm(TN, HOU + (size_t)ob * 32768, LOU + (size_t)ob * 32768,
             bo_up + (size_t)ob * OUT_EMB, nullptr, nullptr, nullptr,
             T1, N_NODES, OUT_EMB, H_DIM, F_BIAS);
        float* src = T1; float* dst = T2;
        for (int l = 0; l < 3; ++l) {
            gemm(src, HOL + (size_t)(ob * 3 + l) * 65536, LOL + (size_t)(ob * 3 + l) * 65536,
                 bo_lins + (size_t)(ob * 3 + l) * OUT_EMB, nullptr, nullptr, nullptr,
                 dst, N_NODES, OUT_EMB, OUT_EMB, F_BIAS | F_SILU);
            float* tmp = src; src = dst; dst = tmp;
        }
        hipLaunchKernelGGL(out_final, dim3((N_NODES * 64 + 255) / 256), dim3(256), 0, stream,
                           src, Wo_out + (size_t)ob * OUT_EMB, P, N_NODES);
    };

    out_block(0, x_in);

    const float* xcur = x_in;
    for (int b = 0; b < NB; ++b) {
        float* xnext = (b % 2 == 0) ? XB : XA;
        hipLaunchKernelGGL(rbf8_kernel, dim3((E_EDGES + 255) / 256), dim3(256), 0, stream,
                           rbf, W_rbf1 + (size_t)b * NRAD * BAS, R8, E_EDGES);
        // x_ji = silu(x @ W_ji + b_ji)
        gemm(xcur, HJI + (size_t)b * 16384, LJI + (size_t)b * 16384, b_ji + (size_t)b * H_DIM,
             nullptr, nullptr, nullptr, E1, E_EDGES, H_DIM, H_DIM, F_BIAS | F_SILU);
        // x_kj_g = silu(x @ W_kj + b_kj) * (rbf8 @ W_rbf2)
        gemm(xcur, HKJ + (size_t)b * 16384, LKJ + (size_t)b * 16384, b_kj + (size_t)b * H_DIM,
             nullptr, R8, W_rbf2 + (size_t)b * BAS * H_DIM,
             E2, E_EDGES, H_DIM, H_DIM, F_BIAS | F_SILU | F_GATE);
        // x_kj_d = silu(x_kj_g @ W_down)
        gemm(E2, HDN + (size_t)b * 8192, LDN + (size_t)b * 8192, nullptr,
             nullptr, nullptr, nullptr, C1, E_EDGES, INT_DIM, H_DIM, F_SILU);
        hipLaunchKernelGGL(sbf8_kernel, dim3((T_TRIP + 255) / 256), dim3(256), 0, stream,
                           sbf, W_sbf1 + (size_t)b * SBF_D * BAS, S8, T_TRIP);
        hipMemsetAsync(C2, 0, (size_t)E_EDGES * INT_DIM * 4, stream);
        hipLaunchKernelGGL(triplet_scatter, dim3(4096), dim3(256), 0, stream,
                           S8, W_sbf2 + (size_t)b * BAS * INT_DIM, C1, idx_kj, idx_ji, C2, T_TRIP);
        // h = x_ji + silu(agg @ W_up)
        gemm(C2, HUP + (size_t)b * 8192, LUP + (size_t)b * 8192, nullptr,
             E1, nullptr, nullptr, E1, E_EDGES, H_DIM, INT_DIM, F_SILU | F_RES);
        // before-skip residual layer
        gemm(E1, HWB + (size_t)(b * 2 + 0) * 16384, LWB + (size_t)(b * 2 + 0) * 16384,
             bb + (size_t)(b * 2 + 0) * H_DIM,
             nullptr, nullptr, nullptr, E2, E_EDGES, H_DIM, H_DIM, F_BIAS | F_SILU);
        gemm(E2, HWB + (size_t)(b * 2 + 1) * 16384, LWB + (size_t)(b * 2 + 1) * 16384,
             bb + (size_t)(b * 2 + 1) * H_DIM,
             E1, nullptr, nullptr, E1, E_EDGES, H_DIM, H_DIM, F_BIAS | F_SILU | F_RES);
        // skip: x_next = silu(h @ W_lin + b_lin) + x
        gemm(E1, HLN + (size_t)b * 16384, LLN + (size_t)b * 16384, b_lin + (size_t)b * H_DIM,
             xcur, nullptr, nullptr, xnext, E_EDGES, H_DIM, H_DIM, F_BIAS | F_SILU | F_RES);
        // after-skip residual layers
        for (int l = 0; l < 2; ++l) {
            gemm(xnext, HWA + (size_t)(b * 4 + 2 * l) * 16384, LWA + (size_t)(b * 4 + 2 * l) * 16384,
                 ba + (size_t)(b * 4 + 2 * l) * H_DIM,
                 nullptr, nullptr, nullptr, E2, E_EDGES, H_DIM, H_DIM, F_BIAS | F_SILU);
            gemm(E2, HWA + (size_t)(b * 4 + 2 * l + 1) * 16384, LWA + (size_t)(b * 4 + 2 * l + 1) * 16384,
                 ba + (size_t)(b * 4 + 2 * l + 1) * H_DIM,
                 xnext, nullptr, nullptr, xnext, E_EDGES, H_DIM, H_DIM, F_BIAS | F_SILU | F_RES);
        }
        xcur = xnext;
        out_block(b + 1, xcur);
    }
}

// Round 3
// 6835.392 us; speedup vs baseline: 1.3161x; 1.1143x over previous
//
#include <hip/hip_runtime.h>
#include <hip/hip_bf16.h>

// Problem constants (fixed by the reference)
#define E_EDGES 200000
#define T_TRIP  2000000
#define N_NODES 20000
#define H_DIM   128
#define INT_DIM 64
#define BAS     8
#define OUT_EMB 256
#define NRAD    6
#define SBF_D   42
#define NB      4

// epilogue flags
#define F_BIAS 1
#define F_SILU 2
#define F_RES  4
#define F_GATE 8

typedef __attribute__((ext_vector_type(8))) __bf16 bf16x8;
typedef __attribute__((ext_vector_type(4))) float f32x4;

__device__ __forceinline__ float silu_f(float v) { return v / (1.0f + __expf(-v)); }

__device__ __forceinline__ unsigned short f2bf(float f) {
    unsigned int u = __float_as_uint(f);
    u += 0x7FFF + ((u >> 16) & 1);   // RNE
    return (unsigned short)(u >> 16);
}
__device__ __forceinline__ float bf2f(unsigned short h) {
    return __uint_as_float(((unsigned int)h) << 16);
}

// ---------------------------------------------------------------------------
// Weight prep: src [cnt][K][N] f32 row-major -> hi/lo [cnt][N][K] split-bf16
// ---------------------------------------------------------------------------
__global__ __launch_bounds__(256) void wprep(
    const float* __restrict__ src, unsigned short* __restrict__ hi,
    unsigned short* __restrict__ lo, int K, int N)
{
    int e = blockIdx.x * 256 + threadIdx.x;
    int total = K * N;
    if (e >= total) return;
    size_t base = (size_t)blockIdx.y * total;
    float a = src[base + e];
    int k = e / N, n = e - k * N;
    unsigned short h = f2bf(a);
    unsigned short l = f2bf(a - bf2f(h));
    hi[base + (size_t)n * K + k] = h;
    lo[base + (size_t)n * K + k] = l;
}

// ---------------------------------------------------------------------------
// Split-bf16 MFMA GEMM (unchanged from round 2)
// ---------------------------------------------------------------------------
__global__ __launch_bounds__(256) void mfma_gemm(
    const float* __restrict__ A,
    const unsigned short* __restrict__ Bhi, const unsigned short* __restrict__ Blo,
    const float* __restrict__ bias, const float* __restrict__ res,
    const float* __restrict__ rbf8v, const float* __restrict__ Wr2,
    float* __restrict__ C, int M, int N, int K, int flags)
{
    __shared__ unsigned short AsH[128 * 32];
    __shared__ unsigned short AsL[128 * 32];

    const int tid  = threadIdx.x;
    const int lane = tid & 63;
    const int w    = tid >> 6;
    const int wm   = w >> 1, wn = w & 1;
    const int bm   = blockIdx.y * 128;
    const int bn   = blockIdx.x * 64;
    const int l15  = lane & 15;
    const int khalf = (lane >> 4) * 8;

    const int sr = tid >> 1;
    const int sc = (tid & 1) * 16;
    int grow = bm + sr; if (grow >= M) grow = M - 1;
    const float* gA = &A[(size_t)grow * K + sc];

    int bcol[2];
    #pragma unroll
    for (int n = 0; n < 2; ++n) bcol[n] = bn + wn * 32 + n * 16 + l15;

    f32x4 acc[4][2] = {};

    for (int k0 = 0; k0 < K; k0 += 32) {
        __syncthreads();
        {
            const float* p = gA + k0;
            float4 f0 = *reinterpret_cast<const float4*>(p);
            float4 f1 = *reinterpret_cast<const float4*>(p + 4);
            float4 f2 = *reinterpret_cast<const float4*>(p + 8);
            float4 f3 = *reinterpret_cast<const float4*>(p + 12);
            float vv[16] = {f0.x,f0.y,f0.z,f0.w, f1.x,f1.y,f1.z,f1.w,
                            f2.x,f2.y,f2.z,f2.w, f3.x,f3.y,f3.z,f3.w};
            const int swz = (sr & 7) << 4;
            #pragma unroll
            for (int q = 0; q < 4; ++q) {
                unsigned short h[4], l[4];
                #pragma unroll
                for (int j = 0; j < 4; ++j) {
                    float a = vv[q * 4 + j];
                    h[j] = f2bf(a);
                    l[j] = f2bf(a - bf2f(h[j]));
                }
                int off = (sr * 64 + (sc / 4 + q) * 8) ^ swz;
                *reinterpret_cast<ushort4*>((char*)AsH + off) = make_ushort4(h[0], h[1], h[2], h[3]);
                *reinterpret_cast<ushort4*>((char*)AsL + off) = make_ushort4(l[0], l[1], l[2], l[3]);
            }
        }
        __syncthreads();

        bf16x8 bh[2], bl[2];
        #pragma unroll
        for (int n = 0; n < 2; ++n) {
            size_t bo = (size_t)bcol[n] * K + k0 + khalf;
            bh[n] = *reinterpret_cast<const bf16x8*>(Bhi + bo);
            bl[n] = *reinterpret_cast<const bf16x8*>(Blo + bo);
        }

        #pragma unroll
        for (int m = 0; m < 4; ++m) {
            int ri  = wm * 64 + m * 16 + l15;
            int off = (ri * 64 + khalf * 2) ^ ((ri & 7) << 4);
            bf16x8 ah = *reinterpret_cast<const bf16x8*>((const char*)AsH + off);
            bf16x8 al = *reinterpret_cast<const bf16x8*>((const char*)AsL + off);
            #pragma unroll
            for (int n = 0; n < 2; ++n) {
                acc[m][n] = __builtin_amdgcn_mfma_f32_16x16x32_bf16(ah, bh[n], acc[m][n], 0, 0, 0);
                acc[m][n] = __builtin_amdgcn_mfma_f32_16x16x32_bf16(al, bh[n], acc[m][n], 0, 0, 0);
                acc[m][n] = __builtin_amdgcn_mfma_f32_16x16x32_bf16(ah, bl[n], acc[m][n], 0, 0, 0);
            }
        }
    }

    const int r4 = (lane >> 4) * 4;
    #pragma unroll
    for (int m = 0; m < 4; ++m) {
        #pragma unroll
        for (int r = 0; r < 4; ++r) {
            int row = bm + wm * 64 + m * 16 + r4 + r;
            if (row >= M) continue;
            #pragma unroll
            for (int n = 0; n < 2; ++n) {
                int col = bn + wn * 32 + n * 16 + l15;
                float v = acc[m][n][r];
                if (flags & F_BIAS) v += bias[col];
                if (flags & F_SILU) v = silu_f(v);
                if (flags & F_GATE) {
                    float g = 0.f;
                    #pragma unroll
                    for (int j = 0; j < 8; ++j)
                        g = fmaf(rbf8v[(size_t)row * 8 + j], Wr2[j * N + col], g);
                    v *= g;
                }
                if (flags & F_RES) v += res[(size_t)row * N + col];
                C[(size_t)row * N + col] = v;
            }
        }
    }
}

// rbf8[e][j] = rbf[e] @ W_rbf1[b]   [E,8]
__global__ __launch_bounds__(256) void rbf8_kernel(
    const float* __restrict__ rbf, const float* __restrict__ W1,
    float* __restrict__ r8, int Ecount)
{
    int e = blockIdx.x * blockDim.x + threadIdx.x;
    if (e >= Ecount) return;
    float rv[NRAD];
    #pragma unroll
    for (int k = 0; k < NRAD; ++k) rv[k] = rbf[(size_t)e * NRAD + k];
    float acc[BAS] = {};
    #pragma unroll
    for (int k = 0; k < NRAD; ++k)
        #pragma unroll
        for (int j = 0; j < BAS; ++j)
            acc[j] = fmaf(rv[k], W1[k * BAS + j], acc[j]);
    float4* o = reinterpret_cast<float4*>(&r8[(size_t)e * BAS]);
    o[0] = make_float4(acc[0], acc[1], acc[2], acc[3]);
    o[1] = make_float4(acc[4], acc[5], acc[6], acc[7]);
}

// sbf8[t][j] = sbf[t] @ W_sbf1[b]   [T,8]
__global__ __launch_bounds__(256) void sbf8_kernel(
    const float* __restrict__ sbf, const float* __restrict__ W1,
    float* __restrict__ s8, int Tcount)
{
    int t = blockIdx.x * blockDim.x + threadIdx.x;
    if (t >= Tcount) return;
    float acc[BAS] = {};
    const float* srow = &sbf[(size_t)t * SBF_D];
    for (int k = 0; k < SBF_D; ++k) {
        float sv = srow[k];
        #pragma unroll
        for (int j = 0; j < BAS; ++j)
            acc[j] = fmaf(sv, W1[k * BAS + j], acc[j]);
    }
    float4* o = reinterpret_cast<float4*>(&s8[(size_t)t * BAS]);
    o[0] = make_float4(acc[0], acc[1], acc[2], acc[3]);
    o[1] = make_float4(acc[4], acc[5], acc[6], acc[7]);
}

// ---------------------------------------------------------------------------
// CSR build kernels
// ---------------------------------------------------------------------------
__global__ __launch_bounds__(256) void csr_count(
    const int* __restrict__ idx, int* __restrict__ cnt, int n)
{
    int i = blockIdx.x * 256 + threadIdx.x;
    if (i < n) atomicAdd(&cnt[idx[i]], 1);
}

// exclusive scan, stage 1: per-block scan of 256 elems
__global__ __launch_bounds__(256) void scan_block(
    const int* __restrict__ cnt, int* __restrict__ ptr, int* __restrict__ bsum, int n)
{
    __shared__ int s[256];
    int i = blockIdx.x * 256 + threadIdx.x;
    int v = (i < n) ? cnt[i] : 0;
    s[threadIdx.x] = v;
    __syncthreads();
    #pragma unroll
    for (int off = 1; off < 256; off <<= 1) {
        int t = (threadIdx.x >= off) ? s[threadIdx.x - off] : 0;
        __syncthreads();
        s[threadIdx.x] += t;
        __syncthreads();
    }
    if (i < n) ptr[i] = s[threadIdx.x] - v;   // exclusive
    if (threadIdx.x == 255) bsum[blockIdx.x] = s[255];
}

// stage 2: single-block exclusive scan of block sums (nb <= 1024)
__global__ __launch_bounds__(1024) void scan_aux(int* __restrict__ bsum, int nb)
{
    __shared__ int s[1024];
    int v = (threadIdx.x < nb) ? bsum[threadIdx.x] : 0;
    s[threadIdx.x] = v;
    __syncthreads();
    #pragma unroll
    for (int off = 1; off < 1024; off <<= 1) {
        int t = (threadIdx.x >= off) ? s[threadIdx.x - off] : 0;
        __syncthreads();
        s[threadIdx.x] += t;
        __syncthreads();
    }
    if (threadIdx.x < nb) bsum[threadIdx.x] = s[threadIdx.x] - v;
}

// stage 3: add block offsets
__global__ __launch_bounds__(256) void scan_add(
    int* __restrict__ ptr, const int* __restrict__ bsum, int n)
{
    int i = blockIdx.x * 256 + threadIdx.x;
    if (i < n) ptr[i] += bsum[blockIdx.x];
}

__global__ __launch_bounds__(256) void csr_fill(
    const int* __restrict__ idx, int* __restrict__ cursor,
    int* __restrict__ perm, int n)
{
    int i = blockIdx.x * 256 + threadIdx.x;
    if (i >= n) return;
    int pos = atomicAdd(&cursor[idx[i]], 1);
    perm[pos] = i;
}

// ---------------------------------------------------------------------------
// Triplet aggregation as CSR gather: one wave per edge, lane = channel.
// agg[e][c] = sum_{t in triplets(e)} xkj[idx_kj[t]][c] * (s8[t] @ Wsb2)[c]
// ---------------------------------------------------------------------------
__global__ __launch_bounds__(256) void triplet_gather(
    const float* __restrict__ s8, const float* __restrict__ Wsb2,
    const float* __restrict__ xkj, const int* __restrict__ idx_kj,
    const int* __restrict__ tptr, const int* __restrict__ tcnt,
    const int* __restrict__ tperm, float* __restrict__ agg, int Ecount)
{
    const int lane = threadIdx.x & 63;
    int wid = (blockIdx.x * blockDim.x + threadIdx.x) >> 6;
    const int nw = (gridDim.x * blockDim.x) >> 6;
    float w2[BAS];
    #pragma unroll
    for (int j = 0; j < BAS; ++j) w2[j] = Wsb2[j * INT_DIM + lane];

    for (int e = wid; e < Ecount; e += nw) {
        int start = tptr[e];
        int end   = start + tcnt[e];
        float acc0 = 0.f, acc1 = 0.f;
        int i = start;
        for (; i + 1 < end; i += 2) {
            int t0 = tperm[i], t1 = tperm[i + 1];
            const float4* sp0 = reinterpret_cast<const float4*>(&s8[(size_t)t0 * BAS]);
            const float4* sp1 = reinterpret_cast<const float4*>(&s8[(size_t)t1 * BAS]);
            float4 a0 = sp0[0], b0 = sp0[1];
            float4 a1 = sp1[0], b1 = sp1[1];
            int e0 = idx_kj[t0], e1 = idx_kj[t1];
            float s0 = a0.x*w2[0] + a0.y*w2[1] + a0.z*w2[2] + a0.w*w2[3]
                     + b0.x*w2[4] + b0.y*w2[5] + b0.z*w2[6] + b0.w*w2[7];
            float s1 = a1.x*w2[0] + a1.y*w2[1] + a1.z*w2[2] + a1.w*w2[3]
                     + b1.x*w2[4] + b1.y*w2[5] + b1.z*w2[6] + b1.w*w2[7];
            acc0 = fmaf(xkj[(size_t)e0 * INT_DIM + lane], s0, acc0);
            acc1 = fmaf(xkj[(size_t)e1 * INT_DIM + lane], s1, acc1);
        }
        if (i < end) {
            int t0 = tperm[i];
            const float4* sp0 = reinterpret_cast<const float4*>(&s8[(size_t)t0 * BAS]);
            float4 a0 = sp0[0], b0 = sp0[1];
            int e0 = idx_kj[t0];
            float s0 = a0.x*w2[0] + a0.y*w2[1] + a0.z*w2[2] + a0.w*w2[3]
                     + b0.x*w2[4] + b0.y*w2[5] + b0.z*w2[6] + b0.w*w2[7];
            acc0 = fmaf(xkj[(size_t)e0 * INT_DIM + lane], s0, acc0);
        }
        agg[(size_t)e * INT_DIM + lane] = acc0 + acc1;
    }
}

// ---------------------------------------------------------------------------
// Output-block node gather: one wave per node, lane covers channels h, h+64.
// tN[n][h] = sum_{e in edges(n)} (rbf[e] @ Wor)[h] * x[e][h]
// ---------------------------------------------------------------------------
__global__ __launch_bounds__(256) void out_gather(
    const float* __restrict__ rbf, const float* __restrict__ Wor,
    const float* __restrict__ x,
    const int* __restrict__ eptr, const int* __restrict__ ecnt,
    const int* __restrict__ eperm, float* __restrict__ tN, int Nn)
{
    const int lane = threadIdx.x & 63;
    int wid = (blockIdx.x * blockDim.x + threadIdx.x) >> 6;
    const int nw = (gridDim.x * blockDim.x) >> 6;
    float wr0[NRAD], wr1[NRAD];
    #pragma unroll
    for (int k = 0; k < NRAD; ++k) {
        wr0[k] = Wor[k * H_DIM + lane];
        wr1[k] = Wor[k * H_DIM + lane + 64];
    }
    for (int n = wid; n < Nn; n += nw) {
        int start = eptr[n];
        int end   = start + ecnt[n];
        float a0 = 0.f, a1 = 0.f;
        for (int i = start; i < end; ++i) {
            int e = eperm[i];
            const float2* rp = reinterpret_cast<const float2*>(&rbf[(size_t)e * NRAD]);
            float2 r0 = rp[0], r1 = rp[1], r2 = rp[2];
            float rA = r0.x*wr0[0] + r0.y*wr0[1] + r1.x*wr0[2]
                     + r1.y*wr0[3] + r2.x*wr0[4] + r2.y*wr0[5];
            float rB = r0.x*wr1[0] + r0.y*wr1[1] + r1.x*wr1[2]
                     + r1.y*wr1[3] + r2.x*wr1[4] + r2.y*wr1[5];
            a0 = fmaf(rA, x[(size_t)e * H_DIM + lane], a0);
            a1 = fmaf(rB, x[(size_t)e * H_DIM + lane + 64], a1);
        }
        tN[(size_t)n * H_DIM + lane] = a0;
        tN[(size_t)n * H_DIM + lane + 64] = a1;
    }
}

// P[n] += dot(Tb[n][:256], Wo[:256]) — one wave per node
__global__ __launch_bounds__(256) void out_final(
    const float* __restrict__ Tb, const float* __restrict__ Wo,
    float* __restrict__ P, int Nn)
{
    const int lane = threadIdx.x & 63;
    int node = (blockIdx.x * blockDim.x + threadIdx.x) >> 6;
    if (node >= Nn) return;
    float s = 0.f;
    #pragma unroll
    for (int i = 0; i < 4; ++i) {
        int c = lane + i * 64;
        s = fmaf(Tb[(size_t)node * OUT_EMB + c], Wo[c], s);
    }
    #pragma unroll
    for (int o = 32; o > 0; o >>= 1) s += __shfl_xor(s, o);
    if (lane == 0) P[node] += s;
}

// ---------------------------------------------------------------------------
extern "C" void kernel_launch(void* const* d_in, const int* in_sizes, int n_in,
                              void* d_out, int out_size, void* d_ws, size_t ws_size,
                              hipStream_t stream)
{
    const float* x_in    = (const float*)d_in[0];
    const float* rbf     = (const float*)d_in[1];
    const float* sbf     = (const float*)d_in[2];
    const float* W_rbf1  = (const float*)d_in[3];
    const float* W_rbf2  = (const float*)d_in[4];
    const float* W_sbf1  = (const float*)d_in[5];
    const float* W_sbf2  = (const float*)d_in[6];
    const float* W_kj    = (const float*)d_in[7];
    const float* b_kj    = (const float*)d_in[8];
    const float* W_ji    = (const float*)d_in[9];
    const float* b_ji    = (const float*)d_in[10];
    const float* W_down  = (const float*)d_in[11];
    const float* W_up    = (const float*)d_in[12];
    const float* Wb      = (const float*)d_in[13];
    const float* bb      = (const float*)d_in[14];
    const float* Wa      = (const float*)d_in[15];
    const float* ba      = (const float*)d_in[16];
    const float* W_lin   = (const float*)d_in[17];
    const float* b_lin   = (const float*)d_in[18];
    const float* Wo_rbf  = (const float*)d_in[19];
    const float* Wo_up   = (const float*)d_in[20];
    const float* bo_up   = (const float*)d_in[21];
    const float* Wo_lins = (const float*)d_in[22];
    const float* bo_lins = (const float*)d_in[23];
    const float* Wo_out  = (const float*)d_in[24];
    const int*   idx_kj  = (const int*)d_in[25];
    const int*   idx_ji  = (const int*)d_in[26];
    const int*   idx_i   = (const int*)d_in[27];

    // workspace carve-up
    char* ws = (char*)d_ws;
    size_t off = 0;
    auto alloc = [&](size_t bytes) -> void* {
        void* p = (void*)(ws + off);
        off += (bytes + 255) & ~(size_t)255;
        return p;
    };
    float* XA = (float*)alloc((size_t)E_EDGES * H_DIM * 4);
    float* XB = (float*)alloc((size_t)E_EDGES * H_DIM * 4);
    float* E1 = (float*)alloc((size_t)E_EDGES * H_DIM * 4);
    float* E2 = (float*)alloc((size_t)E_EDGES * H_DIM * 4);
    float* C1 = (float*)alloc((size_t)E_EDGES * INT_DIM * 4);
    float* C2 = (float*)alloc((size_t)E_EDGES * INT_DIM * 4);
    float* R8 = (float*)alloc((size_t)E_EDGES * BAS * 4);
    float* S8 = (float*)alloc((size_t)T_TRIP * BAS * 4);
    float* TN = (float*)alloc((size_t)N_NODES * H_DIM * 4);
    float* T1 = (float*)alloc((size_t)N_NODES * OUT_EMB * 4);
    float* T2 = (float*)alloc((size_t)N_NODES * OUT_EMB * 4);
    // split-bf16 transposed weights
    typedef unsigned short u16;
    u16* HKJ = (u16*)alloc(4  * 16384 * 2); u16* LKJ = (u16*)alloc(4  * 16384 * 2);
    u16* HJI = (u16*)alloc(4  * 16384 * 2); u16* LJI = (u16*)alloc(4  * 16384 * 2);
    u16* HDN = (u16*)alloc(4  * 8192  * 2); u16* LDN = (u16*)alloc(4  * 8192  * 2);
    u16* HUP = (u16*)alloc(4  * 8192  * 2); u16* LUP = (u16*)alloc(4  * 8192  * 2);
    u16* HWB = (u16*)alloc(8  * 16384 * 2); u16* LWB = (u16*)alloc(8  * 16384 * 2);
    u16* HWA = (u16*)alloc(16 * 16384 * 2); u16* LWA = (u16*)alloc(16 * 16384 * 2);
    u16* HLN = (u16*)alloc(4  * 16384 * 2); u16* LLN = (u16*)alloc(4  * 16384 * 2);
    u16* HOU = (u16*)alloc(5  * 32768 * 2); u16* LOU = (u16*)alloc(5  * 32768 * 2);
    u16* HOL = (u16*)alloc(15 * 65536 * 2); u16* LOL = (u16*)alloc(15 * 65536 * 2);
    // CSR structures
    int* tcnt  = (int*)alloc((size_t)E_EDGES * 4);
    int* tptr  = (int*)alloc((size_t)E_EDGES * 4);
    int* tcur  = (int*)alloc((size_t)E_EDGES * 4);
    int* tperm = (int*)alloc((size_t)T_TRIP * 4);
    int* tbsum = (int*)alloc(1024 * 4);
    int* ecnt  = (int*)alloc((size_t)N_NODES * 4);
    int* eptr  = (int*)alloc((size_t)N_NODES * 4);
    int* ecur  = (int*)alloc((size_t)N_NODES * 4);
    int* eperm = (int*)alloc((size_t)E_EDGES * 4);
    int* ebsum = (int*)alloc(1024 * 4);
    (void)ws_size;

    auto prep = [&](const float* src, u16* hi, u16* lo, int K, int N, int cnt) {
        dim3 g((K * N + 255) / 256, cnt);
        hipLaunchKernelGGL(wprep, g, dim3(256), 0, stream, src, hi, lo, K, N);
    };
    prep(W_kj,    HKJ, LKJ, 128, 128, 4);
    prep(W_ji,    HJI, LJI, 128, 128, 4);
    prep(W_down,  HDN, LDN, 128, 64,  4);
    prep(W_up,    HUP, LUP, 64,  128, 4);
    prep(Wb,      HWB, LWB, 128, 128, 8);
    prep(Wa,      HWA, LWA, 128, 128, 16);
    prep(W_lin,   HLN, LLN, 128, 128, 4);
    prep(Wo_up,   HOU, LOU, 128, 256, 5);
    prep(Wo_lins, HOL, LOL, 256, 256, 15);

    // ---- build triplet CSR (idx_ji: T entries -> E buckets)
    {
        const int nbT = (E_EDGES + 255) / 256;  // 782
        hipMemsetAsync(tcnt, 0, (size_t)E_EDGES * 4, stream);
        hipLaunchKernelGGL(csr_count, dim3((T_TRIP + 255) / 256), dim3(256), 0, stream,
                           idx_ji, tcnt, T_TRIP);
        hipLaunchKernelGGL(scan_block, dim3(nbT), dim3(256), 0, stream, tcnt, tptr, tbsum, E_EDGES);
        hipLaunchKernelGGL(scan_aux, dim3(1), dim3(1024), 0, stream, tbsum, nbT);
        hipLaunchKernelGGL(scan_add, dim3(nbT), dim3(256), 0, stream, tptr, tbsum, E_EDGES);
        hipMemcpyAsync(tcur, tptr, (size_t)E_EDGES * 4, hipMemcpyDeviceToDevice, stream);
        hipLaunchKernelGGL(csr_fill, dim3((T_TRIP + 255) / 256), dim3(256), 0, stream,
                           idx_ji, tcur, tperm, T_TRIP);
    }
    // ---- build node CSR (idx_i: E entries -> N buckets)
    {
        const int nbN = (N_NODES + 255) / 256;  // 79
        hipMemsetAsync(ecnt, 0, (size_t)N_NODES * 4, stream);
        hipLaunchKernelGGL(csr_count, dim3((E_EDGES + 255) / 256), dim3(256), 0, stream,
                           idx_i, ecnt, E_EDGES);
        hipLaunchKernelGGL(scan_block, dim3(nbN), dim3(256), 0, stream, ecnt, eptr, ebsum, N_NODES);
        hipLaunchKernelGGL(scan_aux, dim3(1), dim3(1024), 0, stream, ebsum, nbN);
        hipLaunchKernelGGL(scan_add, dim3(nbN), dim3(256), 0, stream, eptr, ebsum, N_NODES);
        hipMemcpyAsync(ecur, eptr, (size_t)N_NODES * 4, hipMemcpyDeviceToDevice, stream);
        hipLaunchKernelGGL(csr_fill, dim3((E_EDGES + 255) / 256), dim3(256), 0, stream,
                           idx_i, ecur, eperm, E_EDGES);
    }

    auto gemm = [&](const float* A, const u16* Bh, const u16* Bl, const float* bias,
                    const float* res, const float* r8, const float* Wr2f,
                    float* C, int M, int N, int K, int flags) {
        dim3 g(N / 64, (M + 127) / 128), b(256);
        hipLaunchKernelGGL(mfma_gemm, g, b, 0, stream,
                           A, Bh, Bl, bias, res, r8, Wr2f, C, M, N, K, flags);
    };

    float* P = (float*)d_out;
    hipMemsetAsync(P, 0, (size_t)N_NODES * sizeof(float), stream);

    auto out_block = [&](int ob, const float* xcur) {
        hipLaunchKernelGGL(out_gather, dim3(2048), dim3(256), 0, stream,
                           rbf, Wo_rbf + (size_t)ob * NRAD * H_DIM, xcur,
                           eptr, ecnt, eperm, TN, N_NODES);
        gemm(TN, HOU + (size_t)ob * 32768, LOU + (size_t)ob * 32768,
             bo_up + (size_t)ob * OUT_EMB, nullptr, nullptr, nullptr,
             T1, N_NODES, OUT_EMB, H_DIM, F_BIAS);
        float* src = T1; float* dst = T2;
        for (int l = 0; l < 3; ++l) {
            gemm(src, HOL + (size_t)(ob * 3 + l) * 65536, LOL + (size_t)(ob * 3 + l) * 65536,
                 bo_lins + (size_t)(ob * 3 + l) * OUT_EMB, nullptr, nullptr, nullptr,
                 dst, N_NODES, OUT_EMB, OUT_EMB, F_BIAS | F_SILU);
            float* tmp = src; src = dst; dst = tmp;
        }
        hipLaunchKernelGGL(out_final, dim3((N_NODES * 64 + 255) / 256), dim3(256), 0, stream,
                           src, Wo_out + (size_t)ob * OUT_EMB, P, N_NODES);
    };

    out_block(0, x_in);

    const float* xcur = x_in;
    for (int b = 0; b < NB; ++b) {
        float* xnext = (b % 2 == 0) ? XB : XA;
        hipLaunchKernelGGL(rbf8_kernel, dim3((E_EDGES + 255) / 256), dim3(256), 0, stream,
                           rbf, W_rbf1 + (size_t)b * NRAD * BAS, R8, E_EDGES);
        // x_ji = silu(x @ W_ji + b_ji)
        gemm(xcur, HJI + (size_t)b * 16384, LJI + (size_t)b * 16384, b_ji + (size_t)b * H_DIM,
             nullptr, nullptr, nullptr, E1, E_EDGES, H_DIM, H_DIM, F_BIAS | F_SILU);
        // x_kj_g = silu(x @ W_kj + b_kj) * (rbf8 @ W_rbf2)
        gemm(xcur, HKJ + (size_t)b * 16384, LKJ + (size_t)b * 16384, b_kj + (size_t)b * H_DIM,
             nullptr, R8, W_rbf2 + (size_t)b * BAS * H_DIM,
             E2, E_EDGES, H_DIM, H_DIM, F_BIAS | F_SILU | F_GATE);
        // x_kj_d = silu(x_kj_g @ W_down)
        gemm(E2, HDN + (size_t)b * 8192, LDN + (size_t)b * 8192, nullptr,
             nullptr, nullptr, nullptr, C1, E_EDGES, INT_DIM, H_DIM, F_SILU);
        hipLaunchKernelGGL(sbf8_kernel, dim3((T_TRIP + 255) / 256), dim3(256), 0, stream,
                           sbf, W_sbf1 + (size_t)b * SBF_D * BAS, S8, T_TRIP);
        // triplet aggregation (CSR gather, atomic-free)
        hipLaunchKernelGGL(triplet_gather, dim3(2048), dim3(256), 0, stream,
                           S8, W_sbf2 + (size_t)b * BAS * INT_DIM, C1, idx_kj,
                           tptr, tcnt, tperm, C2, E_EDGES);
        // h = x_ji + silu(agg @ W_up)
        gemm(C2, HUP + (size_t)b * 8192, LUP + (size_t)b * 8192, nullptr,
             E1, nullptr, nullptr, E1, E_EDGES, H_DIM, INT_DIM, F_SILU | F_RES);
        // before-skip residual layer
        gemm(E1, HWB + (size_t)(b * 2 + 0) * 16384, LWB + (size_t)(b * 2 + 0) * 16384,
             bb + (size_t)(b * 2 + 0) * H_DIM,
             nullptr, nullptr, nullptr, E2, E_EDGES, H_DIM, H_DIM, F_BIAS | F_SILU);
        gemm(E2, HWB + (size_t)(b * 2 + 1) * 16384, LWB + (size_t)(b * 2 + 1) * 16384,
             bb + (size_t)(b * 2 + 1) * H_DIM,
             E1, nullptr, nullptr, E1, E_EDGES, H_DIM, H_DIM, F_BIAS | F_SILU | F_RES);
        // skip: x_next = silu(h @ W_lin + b_lin) + x
        gemm(E1, HLN + (size_t)b * 16384, LLN + (size_t)b * 16384, b_lin + (size_t)b * H_DIM,
             xcur, nullptr, nullptr, xnext, E_EDGES, H_DIM, H_DIM, F_BIAS | F_SILU | F_RES);
        // after-skip residual layers
        for (int l = 0; l < 2; ++l) {
            gemm(xnext, HWA + (size_t)(b * 4 + 2 * l) * 16384, LWA + (size_t)(b * 4 + 2 * l) * 16384,
                 ba + (size_t)(b * 4 + 2 * l) * H_DIM,
                 nullptr, nullptr, nullptr, E2, E_EDGES, H_DIM, H_DIM, F_BIAS | F_SILU);
            gemm(E2, HWA + (size_t)(b * 4 + 2 * l + 1) * 16384, LWA + (size_t)(b * 4 + 2 * l + 1) * 16384,
                 ba + (size_t)(b * 4 + 2 * l + 1) * H_DIM,
                 xnext, nullptr, nullptr, xnext, E_EDGES, H_DIM, H_DIM, F_BIAS | F_SILU | F_RES);
        }
        xcur = xnext;
        out_block(b + 1, xcur);
    }
}

// Round 4
// 5900.150 us; speedup vs baseline: 1.5248x; 1.1585x over previous
//
#include <hip/hip_runtime.h>
#include <hip/hip_bf16.h>

// Problem constants (fixed by the reference)
#define E_EDGES 200000
#define T_TRIP  2000000
#define N_NODES 20000
#define H_DIM   128
#define INT_DIM 64
#define BAS     8
#define OUT_EMB 256
#define NRAD    6
#define SBF_D   42
#define NB      4

// epilogue flags
#define F_BIAS 1
#define F_SILU 2
#define F_RES  4
#define F_GATE 8

typedef __attribute__((ext_vector_type(8))) __bf16 bf16x8;
typedef __attribute__((ext_vector_type(4))) float f32x4;

__device__ __forceinline__ float silu_f(float v) { return v / (1.0f + __expf(-v)); }

__device__ __forceinline__ unsigned short f2bf(float f) {
    unsigned int u = __float_as_uint(f);
    u += 0x7FFF + ((u >> 16) & 1);   // RNE
    return (unsigned short)(u >> 16);
}
__device__ __forceinline__ float bf2f(unsigned short h) {
    return __uint_as_float(((unsigned int)h) << 16);
}

// ---------------------------------------------------------------------------
// Weight prep: src [cnt][K][N] f32 row-major -> hi/lo [cnt][N][K] split-bf16
// ---------------------------------------------------------------------------
__global__ __launch_bounds__(256) void wprep(
    const float* __restrict__ src, unsigned short* __restrict__ hi,
    unsigned short* __restrict__ lo, int K, int N)
{
    int e = blockIdx.x * 256 + threadIdx.x;
    int total = K * N;
    if (e >= total) return;
    size_t base = (size_t)blockIdx.y * total;
    float a = src[base + e];
    int k = e / N, n = e - k * N;
    unsigned short h = f2bf(a);
    unsigned short l = f2bf(a - bf2f(h));
    hi[base + (size_t)n * K + k] = h;
    lo[base + (size_t)n * K + k] = l;
}

// ---------------------------------------------------------------------------
// Split-bf16 MFMA GEMM (as round 2/3)
// ---------------------------------------------------------------------------
__global__ __launch_bounds__(256) void mfma_gemm(
    const float* __restrict__ A,
    const unsigned short* __restrict__ Bhi, const unsigned short* __restrict__ Blo,
    const float* __restrict__ bias, const float* __restrict__ res,
    const float* __restrict__ rbf8v, const float* __restrict__ Wr2,
    float* __restrict__ C, int M, int N, int K, int flags)
{
    __shared__ unsigned short AsH[128 * 32];
    __shared__ unsigned short AsL[128 * 32];

    const int tid  = threadIdx.x;
    const int lane = tid & 63;
    const int w    = tid >> 6;
    const int wm   = w >> 1, wn = w & 1;
    const int bm   = blockIdx.y * 128;
    const int bn   = blockIdx.x * 64;
    const int l15  = lane & 15;
    const int khalf = (lane >> 4) * 8;

    const int sr = tid >> 1;
    const int sc = (tid & 1) * 16;
    int grow = bm + sr; if (grow >= M) grow = M - 1;
    const float* gA = &A[(size_t)grow * K + sc];

    int bcol[2];
    #pragma unroll
    for (int n = 0; n < 2; ++n) bcol[n] = bn + wn * 32 + n * 16 + l15;

    f32x4 acc[4][2] = {};

    for (int k0 = 0; k0 < K; k0 += 32) {
        __syncthreads();
        {
            const float* p = gA + k0;
            float4 f0 = *reinterpret_cast<const float4*>(p);
            float4 f1 = *reinterpret_cast<const float4*>(p + 4);
            float4 f2 = *reinterpret_cast<const float4*>(p + 8);
            float4 f3 = *reinterpret_cast<const float4*>(p + 12);
            float vv[16] = {f0.x,f0.y,f0.z,f0.w, f1.x,f1.y,f1.z,f1.w,
                            f2.x,f2.y,f2.z,f2.w, f3.x,f3.y,f3.z,f3.w};
            const int swz = (sr & 7) << 4;
            #pragma unroll
            for (int q = 0; q < 4; ++q) {
                unsigned short h[4], l[4];
                #pragma unroll
                for (int j = 0; j < 4; ++j) {
                    float a = vv[q * 4 + j];
                    h[j] = f2bf(a);
                    l[j] = f2bf(a - bf2f(h[j]));
                }
                int off = (sr * 64 + (sc / 4 + q) * 8) ^ swz;
                *reinterpret_cast<ushort4*>((char*)AsH + off) = make_ushort4(h[0], h[1], h[2], h[3]);
                *reinterpret_cast<ushort4*>((char*)AsL + off) = make_ushort4(l[0], l[1], l[2], l[3]);
            }
        }
        __syncthreads();

        bf16x8 bh[2], bl[2];
        #pragma unroll
        for (int n = 0; n < 2; ++n) {
            size_t bo = (size_t)bcol[n] * K + k0 + khalf;
            bh[n] = *reinterpret_cast<const bf16x8*>(Bhi + bo);
            bl[n] = *reinterpret_cast<const bf16x8*>(Blo + bo);
        }

        #pragma unroll
        for (int m = 0; m < 4; ++m) {
            int ri  = wm * 64 + m * 16 + l15;
            int off = (ri * 64 + khalf * 2) ^ ((ri & 7) << 4);
            bf16x8 ah = *reinterpret_cast<const bf16x8*>((const char*)AsH + off);
            bf16x8 al = *reinterpret_cast<const bf16x8*>((const char*)AsL + off);
            #pragma unroll
            for (int n = 0; n < 2; ++n) {
                acc[m][n] = __builtin_amdgcn_mfma_f32_16x16x32_bf16(ah, bh[n], acc[m][n], 0, 0, 0);
                acc[m][n] = __builtin_amdgcn_mfma_f32_16x16x32_bf16(al, bh[n], acc[m][n], 0, 0, 0);
                acc[m][n] = __builtin_amdgcn_mfma_f32_16x16x32_bf16(ah, bl[n], acc[m][n], 0, 0, 0);
            }
        }
    }

    const int r4 = (lane >> 4) * 4;
    #pragma unroll
    for (int m = 0; m < 4; ++m) {
        #pragma unroll
        for (int r = 0; r < 4; ++r) {
            int row = bm + wm * 64 + m * 16 + r4 + r;
            if (row >= M) continue;
            #pragma unroll
            for (int n = 0; n < 2; ++n) {
                int col = bn + wn * 32 + n * 16 + l15;
                float v = acc[m][n][r];
                if (flags & F_BIAS) v += bias[col];
                if (flags & F_SILU) v = silu_f(v);
                if (flags & F_GATE) {
                    float g = 0.f;
                    #pragma unroll
                    for (int j = 0; j < 8; ++j)
                        g = fmaf(rbf8v[(size_t)row * 8 + j], Wr2[j * N + col], g);
                    v *= g;
                }
                if (flags & F_RES) v += res[(size_t)row * N + col];
                C[(size_t)row * N + col] = v;
            }
        }
    }
}

// ---------------------------------------------------------------------------
// Fused residual pair: C = A + silu(silu(A@W1+b1)@W2+b2), all dims 128.
// M-tile 64, N=K=128 full. Intermediate kept in LDS as split-bf16.
// ---------------------------------------------------------------------------
__global__ __launch_bounds__(256, 2) void fused_pair(
    const float* __restrict__ A,
    const unsigned short* __restrict__ B1h, const unsigned short* __restrict__ B1l,
    const unsigned short* __restrict__ B2h, const unsigned short* __restrict__ B2l,
    const float* __restrict__ b1, const float* __restrict__ b2,
    float* __restrict__ C, int M)
{
    __shared__ unsigned short AsH[64 * 128];
    __shared__ unsigned short AsL[64 * 128];
    __shared__ unsigned short IsH[64 * 128];
    __shared__ unsigned short IsL[64 * 128];

    const int tid  = threadIdx.x;
    const int lane = tid & 63;
    const int w    = tid >> 6;
    const int wm   = w >> 1, wn = w & 1;
    const int bm   = blockIdx.x * 64;
    const int l15  = lane & 15;
    const int khalf = (lane >> 4) * 8;
    const int r4   = (lane >> 4) * 4;

    // ---- stage A [64][128] fp32 -> split bf16 LDS (swizzled)
    {
        int r  = tid >> 2;
        int c0 = (tid & 3) * 32;
        int grow = bm + r; if (grow >= M) grow = M - 1;
        const float* p = &A[(size_t)grow * H_DIM + c0];
        const int swz = (r & 7) << 4;
        #pragma unroll
        for (int q = 0; q < 8; ++q) {
            float4 f = *reinterpret_cast<const float4*>(p + q * 4);
            float vv[4] = {f.x, f.y, f.z, f.w};
            unsigned short h[4], l[4];
            #pragma unroll
            for (int j = 0; j < 4; ++j) {
                h[j] = f2bf(vv[j]);
                l[j] = f2bf(vv[j] - bf2f(h[j]));
            }
            int off = (r * 256 + c0 * 2 + q * 8) ^ swz;
            *reinterpret_cast<ushort4*>((char*)AsH + off) = make_ushort4(h[0], h[1], h[2], h[3]);
            *reinterpret_cast<ushort4*>((char*)AsL + off) = make_ushort4(l[0], l[1], l[2], l[3]);
        }
    }
    __syncthreads();

    // ---- GEMM1: I = silu(A@W1 + b1)
    f32x4 acc[2][4] = {};
    for (int k0 = 0; k0 < 128; k0 += 32) {
        bf16x8 bh[4], bl[4];
        #pragma unroll
        for (int n = 0; n < 4; ++n) {
            size_t bo = (size_t)(wn * 64 + n * 16 + l15) * 128 + k0 + khalf;
            bh[n] = *reinterpret_cast<const bf16x8*>(B1h + bo);
            bl[n] = *reinterpret_cast<const bf16x8*>(B1l + bo);
        }
        #pragma unroll
        for (int m = 0; m < 2; ++m) {
            int row = wm * 32 + m * 16 + l15;
            int off = (row * 256 + (k0 + khalf) * 2) ^ ((row & 7) << 4);
            bf16x8 ah = *reinterpret_cast<const bf16x8*>((const char*)AsH + off);
            bf16x8 al = *reinterpret_cast<const bf16x8*>((const char*)AsL + off);
            #pragma unroll
            for (int n = 0; n < 4; ++n) {
                acc[m][n] = __builtin_amdgcn_mfma_f32_16x16x32_bf16(ah, bh[n], acc[m][n], 0, 0, 0);
                acc[m][n] = __builtin_amdgcn_mfma_f32_16x16x32_bf16(al, bh[n], acc[m][n], 0, 0, 0);
                acc[m][n] = __builtin_amdgcn_mfma_f32_16x16x32_bf16(ah, bl[n], acc[m][n], 0, 0, 0);
            }
        }
    }
    // silu + split-store intermediate to LDS
    #pragma unroll
    for (int n = 0; n < 4; ++n) {
        int col = wn * 64 + n * 16 + l15;
        float bv = b1[col];
        #pragma unroll
        for (int m = 0; m < 2; ++m) {
            #pragma unroll
            for (int r = 0; r < 4; ++r) {
                int row = wm * 32 + m * 16 + r4 + r;
                float v = silu_f(acc[m][n][r] + bv);
                unsigned short hh = f2bf(v);
                unsigned short ll = f2bf(v - bf2f(hh));
                int off = (row * 256 + col * 2) ^ ((row & 7) << 4);
                *reinterpret_cast<unsigned short*>((char*)IsH + off) = hh;
                *reinterpret_cast<unsigned short*>((char*)IsL + off) = ll;
            }
        }
    }
    __syncthreads();

    // ---- GEMM2: C = A + silu(I@W2 + b2)
    f32x4 acc2[2][4] = {};
    for (int k0 = 0; k0 < 128; k0 += 32) {
        bf16x8 bh[4], bl[4];
        #pragma unroll
        for (int n = 0; n < 4; ++n) {
            size_t bo = (size_t)(wn * 64 + n * 16 + l15) * 128 + k0 + khalf;
            bh[n] = *reinterpret_cast<const bf16x8*>(B2h + bo);
            bl[n] = *reinterpret_cast<const bf16x8*>(B2l + bo);
        }
        #pragma unroll
        for (int m = 0; m < 2; ++m) {
            int row = wm * 32 + m * 16 + l15;
            int off = (row * 256 + (k0 + khalf) * 2) ^ ((row & 7) << 4);
            bf16x8 ah = *reinterpret_cast<const bf16x8*>((const char*)IsH + off);
            bf16x8 al = *reinterpret_cast<const bf16x8*>((const char*)IsL + off);
            #pragma unroll
            for (int n = 0; n < 4; ++n) {
                acc2[m][n] = __builtin_amdgcn_mfma_f32_16x16x32_bf16(ah, bh[n], acc2[m][n], 0, 0, 0);
                acc2[m][n] = __builtin_amdgcn_mfma_f32_16x16x32_bf16(al, bh[n], acc2[m][n], 0, 0, 0);
                acc2[m][n] = __builtin_amdgcn_mfma_f32_16x16x32_bf16(ah, bl[n], acc2[m][n], 0, 0, 0);
            }
        }
    }
    #pragma unroll
    for (int n = 0; n < 4; ++n) {
        int col = wn * 64 + n * 16 + l15;
        float bv = b2[col];
        #pragma unroll
        for (int m = 0; m < 2; ++m) {
            #pragma unroll
            for (int r = 0; r < 4; ++r) {
                int row = wm * 32 + m * 16 + r4 + r;
                int grow = bm + row;
                if (grow >= M) continue;
                float v = silu_f(acc2[m][n][r] + bv);
                int off = (row * 256 + col * 2) ^ ((row & 7) << 4);
                float hres = bf2f(*reinterpret_cast<unsigned short*>((char*)AsH + off))
                           + bf2f(*reinterpret_cast<unsigned short*>((char*)AsL + off));
                C[(size_t)grow * H_DIM + col] = hres + v;
            }
        }
    }
}

// rbf8[e][j] = rbf[e] @ W_rbf1[b]   [E,8]
__global__ __launch_bounds__(256) void rbf8_kernel(
    const float* __restrict__ rbf, const float* __restrict__ W1,
    float* __restrict__ r8, int Ecount)
{
    int e = blockIdx.x * blockDim.x + threadIdx.x;
    if (e >= Ecount) return;
    float rv[NRAD];
    #pragma unroll
    for (int k = 0; k < NRAD; ++k) rv[k] = rbf[(size_t)e * NRAD + k];
    float acc[BAS] = {};
    #pragma unroll
    for (int k = 0; k < NRAD; ++k)
        #pragma unroll
        for (int j = 0; j < BAS; ++j)
            acc[j] = fmaf(rv[k], W1[k * BAS + j], acc[j]);
    float4* o = reinterpret_cast<float4*>(&r8[(size_t)e * BAS]);
    o[0] = make_float4(acc[0], acc[1], acc[2], acc[3]);
    o[1] = make_float4(acc[4], acc[5], acc[6], acc[7]);
}

// ---------------------------------------------------------------------------
// CSR build kernels
// ---------------------------------------------------------------------------
__global__ __launch_bounds__(256) void csr_count(
    const int* __restrict__ idx, int* __restrict__ cnt, int n)
{
    int i = blockIdx.x * 256 + threadIdx.x;
    if (i < n) atomicAdd(&cnt[idx[i]], 1);
}

__global__ __launch_bounds__(256) void scan_block(
    const int* __restrict__ cnt, int* __restrict__ ptr, int* __restrict__ bsum, int n)
{
    __shared__ int s[256];
    int i = blockIdx.x * 256 + threadIdx.x;
    int v = (i < n) ? cnt[i] : 0;
    s[threadIdx.x] = v;
    __syncthreads();
    #pragma unroll
    for (int off = 1; off < 256; off <<= 1) {
        int t = (threadIdx.x >= off) ? s[threadIdx.x - off] : 0;
        __syncthreads();
        s[threadIdx.x] += t;
        __syncthreads();
    }
    if (i < n) ptr[i] = s[threadIdx.x] - v;   // exclusive
    if (threadIdx.x == 255) bsum[blockIdx.x] = s[255];
}

__global__ __launch_bounds__(1024) void scan_aux(int* __restrict__ bsum, int nb)
{
    __shared__ int s[1024];
    int v = (threadIdx.x < nb) ? bsum[threadIdx.x] : 0;
    s[threadIdx.x] = v;
    __syncthreads();
    #pragma unroll
    for (int off = 1; off < 1024; off <<= 1) {
        int t = (threadIdx.x >= off) ? s[threadIdx.x - off] : 0;
        __syncthreads();
        s[threadIdx.x] += t;
        __syncthreads();
    }
    if (threadIdx.x < nb) bsum[threadIdx.x] = s[threadIdx.x] - v;
}

__global__ __launch_bounds__(256) void scan_add(
    int* __restrict__ ptr, const int* __restrict__ bsum, int n)
{
    int i = blockIdx.x * 256 + threadIdx.x;
    if (i < n) ptr[i] += bsum[blockIdx.x];
}

__global__ __launch_bounds__(256) void csr_fill(
    const int* __restrict__ idx, int* __restrict__ cursor,
    int* __restrict__ perm, int n)
{
    int i = blockIdx.x * 256 + threadIdx.x;
    if (i >= n) return;
    int pos = atomicAdd(&cursor[idx[i]], 1);
    perm[pos] = i;
}

// ---------------------------------------------------------------------------
// One-time: permuted sbf basis for ALL blocks + permuted idx_kj.
// ps8[b][i][j] (bf16) = (sbf[tperm[i]] @ W_sbf1[b])[j];  pkj[i]=idx_kj[tperm[i]]
// ---------------------------------------------------------------------------
__global__ __launch_bounds__(256) void permute_s8(
    const float* __restrict__ sbf, const float* __restrict__ W1all,
    const int* __restrict__ idx_kj, const int* __restrict__ tperm,
    unsigned short* __restrict__ ps8, int* __restrict__ pkj, int Tcount)
{
    __shared__ float Ws[NB * SBF_D * BAS];
    for (int i = threadIdx.x; i < NB * SBF_D * BAS; i += 256) Ws[i] = W1all[i];
    __syncthreads();
    int i = blockIdx.x * 256 + threadIdx.x;
    if (i >= Tcount) return;
    int t = tperm[i];
    pkj[i] = idx_kj[t];
    float s[SBF_D];
    {
        const float2* p2 = reinterpret_cast<const float2*>(&sbf[(size_t)t * SBF_D]);
        #pragma unroll
        for (int k = 0; k < SBF_D / 2; ++k) {
            float2 v = p2[k];
            s[2 * k] = v.x; s[2 * k + 1] = v.y;
        }
    }
    #pragma unroll
    for (int b = 0; b < NB; ++b) {
        const float* Wb_ = &Ws[b * SBF_D * BAS];
        float acc[BAS] = {};
        for (int k = 0; k < SBF_D; ++k) {
            float sv = s[k];
            #pragma unroll
            for (int j = 0; j < BAS; ++j)
                acc[j] = fmaf(sv, Wb_[k * BAS + j], acc[j]);
        }
        ushort4 o0 = make_ushort4(f2bf(acc[0]), f2bf(acc[1]), f2bf(acc[2]), f2bf(acc[3]));
        ushort4 o1 = make_ushort4(f2bf(acc[4]), f2bf(acc[5]), f2bf(acc[6]), f2bf(acc[7]));
        unsigned short* op = &ps8[((size_t)b * Tcount + i) * BAS];
        *reinterpret_cast<ushort4*>(op) = o0;
        *reinterpret_cast<ushort4*>(op + 4) = o1;
    }
}

// ---------------------------------------------------------------------------
// Triplet aggregation, fully sequential reads (permuted stream).
// ---------------------------------------------------------------------------
__device__ __forceinline__ float dot8_bf(uint4 r, const float* w2) {
    float s;
    s  = bf2f((unsigned short)(r.x)) * w2[0] + bf2f((unsigned short)(r.x >> 16)) * w2[1];
    s += bf2f((unsigned short)(r.y)) * w2[2] + bf2f((unsigned short)(r.y >> 16)) * w2[3];
    s += bf2f((unsigned short)(r.z)) * w2[4] + bf2f((unsigned short)(r.z >> 16)) * w2[5];
    s += bf2f((unsigned short)(r.w)) * w2[6] + bf2f((unsigned short)(r.w >> 16)) * w2[7];
    return s;
}

__global__ __launch_bounds__(256) void triplet_gather2(
    const unsigned short* __restrict__ ps8b, const float* __restrict__ Wsb2,
    const float* __restrict__ xkj, const int* __restrict__ pkj,
    const int* __restrict__ tptr, const int* __restrict__ tcnt,
    float* __restrict__ agg, int Ecount)
{
    const int lane = threadIdx.x & 63;
    int wid = (blockIdx.x * blockDim.x + threadIdx.x) >> 6;
    const int nw = (gridDim.x * blockDim.x) >> 6;
    float w2[BAS];
    #pragma unroll
    for (int j = 0; j < BAS; ++j) w2[j] = Wsb2[j * INT_DIM + lane];

    for (int e = wid; e < Ecount; e += nw) {
        int start = tptr[e];
        int end   = start + tcnt[e];
        float acc0 = 0.f, acc1 = 0.f;
        int i = start;
        for (; i + 1 < end; i += 2) {
            uint4 ra = *reinterpret_cast<const uint4*>(&ps8b[(size_t)i * BAS]);
            uint4 rb = *reinterpret_cast<const uint4*>(&ps8b[(size_t)(i + 1) * BAS]);
            int e0 = pkj[i], e1 = pkj[i + 1];
            float s0 = dot8_bf(ra, w2);
            float s1 = dot8_bf(rb, w2);
            acc0 = fmaf(xkj[(size_t)e0 * INT_DIM + lane], s0, acc0);
            acc1 = fmaf(xkj[(size_t)e1 * INT_DIM + lane], s1, acc1);
        }
        if (i < end) {
            uint4 ra = *reinterpret_cast<const uint4*>(&ps8b[(size_t)i * BAS]);
            int e0 = pkj[i];
            acc0 = fmaf(xkj[(size_t)e0 * INT_DIM + lane], dot8_bf(ra, w2), acc0);
        }
        agg[(size_t)e * INT_DIM + lane] = acc0 + acc1;
    }
}

// ---------------------------------------------------------------------------
// Output-block node gather (unchanged)
// ---------------------------------------------------------------------------
__global__ __launch_bounds__(256) void out_gather(
    const float* __restrict__ rbf, const float* __restrict__ Wor,
    const float* __restrict__ x,
    const int* __restrict__ eptr, const int* __restrict__ ecnt,
    const int* __restrict__ eperm, float* __restrict__ tN, int Nn)
{
    const int lane = threadIdx.x & 63;
    int wid = (blockIdx.x * blockDim.x + threadIdx.x) >> 6;
    const int nw = (gridDim.x * blockDim.x) >> 6;
    float wr0[NRAD], wr1[NRAD];
    #pragma unroll
    for (int k = 0; k < NRAD; ++k) {
        wr0[k] = Wor[k * H_DIM + lane];
        wr1[k] = Wor[k * H_DIM + lane + 64];
    }
    for (int n = wid; n < Nn; n += nw) {
        int start = eptr[n];
        int end   = start + ecnt[n];
        float a0 = 0.f, a1 = 0.f;
        for (int i = start; i < end; ++i) {
            int e = eperm[i];
            const float2* rp = reinterpret_cast<const float2*>(&rbf[(size_t)e * NRAD]);
            float2 r0 = rp[0], r1 = rp[1], r2 = rp[2];
            float rA = r0.x*wr0[0] + r0.y*wr0[1] + r1.x*wr0[2]
                     + r1.y*wr0[3] + r2.x*wr0[4] + r2.y*wr0[5];
            float rB = r0.x*wr1[0] + r0.y*wr1[1] + r1.x*wr1[2]
                     + r1.y*wr1[3] + r2.x*wr1[4] + r2.y*wr1[5];
            a0 = fmaf(rA, x[(size_t)e * H_DIM + lane], a0);
            a1 = fmaf(rB, x[(size_t)e * H_DIM + lane + 64], a1);
        }
        tN[(size_t)n * H_DIM + lane] = a0;
        tN[(size_t)n * H_DIM + lane + 64] = a1;
    }
}

// P[n] += dot(Tb[n][:256], Wo[:256]) — one wave per node
__global__ __launch_bounds__(256) void out_final(
    const float* __restrict__ Tb, const float* __restrict__ Wo,
    float* __restrict__ P, int Nn)
{
    const int lane = threadIdx.x & 63;
    int node = (blockIdx.x * blockDim.x + threadIdx.x) >> 6;
    if (node >= Nn) return;
    float s = 0.f;
    #pragma unroll
    for (int i = 0; i < 4; ++i) {
        int c = lane + i * 64;
        s = fmaf(Tb[(size_t)node * OUT_EMB + c], Wo[c], s);
    }
    #pragma unroll
    for (int o = 32; o > 0; o >>= 1) s += __shfl_xor(s, o);
    if (lane == 0) P[node] += s;
}

// ---------------------------------------------------------------------------
extern "C" void kernel_launch(void* const* d_in, const int* in_sizes, int n_in,
                              void* d_out, int out_size, void* d_ws, size_t ws_size,
                              hipStream_t stream)
{
    const float* x_in    = (const float*)d_in[0];
    const float* rbf     = (const float*)d_in[1];
    const float* sbf     = (const float*)d_in[2];
    const float* W_rbf1  = (const float*)d_in[3];
    const float* W_rbf2  = (const float*)d_in[4];
    const float* W_sbf1  = (const float*)d_in[5];
    const float* W_sbf2  = (const float*)d_in[6];
    const float* W_kj    = (const float*)d_in[7];
    const float* b_kj    = (const float*)d_in[8];
    const float* W_ji    = (const float*)d_in[9];
    const float* b_ji    = (const float*)d_in[10];
    const float* W_down  = (const float*)d_in[11];
    const float* W_up    = (const float*)d_in[12];
    const float* Wb      = (const float*)d_in[13];
    const float* bb      = (const float*)d_in[14];
    const float* Wa      = (const float*)d_in[15];
    const float* ba      = (const float*)d_in[16];
    const float* W_lin   = (const float*)d_in[17];
    const float* b_lin   = (const float*)d_in[18];
    const float* Wo_rbf  = (const float*)d_in[19];
    const float* Wo_up   = (const float*)d_in[20];
    const float* bo_up   = (const float*)d_in[21];
    const float* Wo_lins = (const float*)d_in[22];
    const float* bo_lins = (const float*)d_in[23];
    const float* Wo_out  = (const float*)d_in[24];
    const int*   idx_kj  = (const int*)d_in[25];
    const int*   idx_ji  = (const int*)d_in[26];
    const int*   idx_i   = (const int*)d_in[27];

    // workspace carve-up
    char* ws = (char*)d_ws;
    size_t off = 0;
    auto alloc = [&](size_t bytes) -> void* {
        void* p = (void*)(ws + off);
        off += (bytes + 255) & ~(size_t)255;
        return p;
    };
    float* XA = (float*)alloc((size_t)E_EDGES * H_DIM * 4);
    float* XB = (float*)alloc((size_t)E_EDGES * H_DIM * 4);
    float* E1 = (float*)alloc((size_t)E_EDGES * H_DIM * 4);
    float* E2 = (float*)alloc((size_t)E_EDGES * H_DIM * 4);
    float* C1 = (float*)alloc((size_t)E_EDGES * INT_DIM * 4);
    float* C2 = (float*)alloc((size_t)E_EDGES * INT_DIM * 4);
    float* R8 = (float*)alloc((size_t)E_EDGES * BAS * 4);
    float* TN = (float*)alloc((size_t)N_NODES * H_DIM * 4);
    float* T1 = (float*)alloc((size_t)N_NODES * OUT_EMB * 4);
    float* T2 = (float*)alloc((size_t)N_NODES * OUT_EMB * 4);
    // split-bf16 transposed weights
    typedef unsigned short u16;
    u16* HKJ = (u16*)alloc(4  * 16384 * 2); u16* LKJ = (u16*)alloc(4  * 16384 * 2);
    u16* HJI = (u16*)alloc(4  * 16384 * 2); u16* LJI = (u16*)alloc(4  * 16384 * 2);
    u16* HDN = (u16*)alloc(4  * 8192  * 2); u16* LDN = (u16*)alloc(4  * 8192  * 2);
    u16* HUP = (u16*)alloc(4  * 8192  * 2); u16* LUP = (u16*)alloc(4  * 8192  * 2);
    u16* HWB = (u16*)alloc(8  * 16384 * 2); u16* LWB = (u16*)alloc(8  * 16384 * 2);
    u16* HWA = (u16*)alloc(16 * 16384 * 2); u16* LWA = (u16*)alloc(16 * 16384 * 2);
    u16* HLN = (u16*)alloc(4  * 16384 * 2); u16* LLN = (u16*)alloc(4  * 16384 * 2);
    u16* HOU = (u16*)alloc(5  * 32768 * 2); u16* LOU = (u16*)alloc(5  * 32768 * 2);
    u16* HOL = (u16*)alloc(15 * 65536 * 2); u16* LOL = (u16*)alloc(15 * 65536 * 2);
    // CSR structures
    int* tcnt  = (int*)alloc((size_t)E_EDGES * 4);
    int* tptr  = (int*)alloc((size_t)E_EDGES * 4);
    int* tcur  = (int*)alloc((size_t)E_EDGES * 4);
    int* tperm = (int*)alloc((size_t)T_TRIP * 4);
    int* tbsum = (int*)alloc(1024 * 4);
    int* ecnt  = (int*)alloc((size_t)N_NODES * 4);
    int* eptr  = (int*)alloc((size_t)N_NODES * 4);
    int* ecur  = (int*)alloc((size_t)N_NODES * 4);
    int* eperm = (int*)alloc((size_t)E_EDGES * 4);
    int* ebsum = (int*)alloc(1024 * 4);
    // permuted triplet stream
    u16* PS8 = (u16*)alloc((size_t)NB * T_TRIP * BAS * 2);  // 128 MB, bf16
    int* PKJ = (int*)alloc((size_t)T_TRIP * 4);
    (void)ws_size;

    auto prep = [&](const float* src, u16* hi, u16* lo, int K, int N, int cnt) {
        dim3 g((K * N + 255) / 256, cnt);
        hipLaunchKernelGGL(wprep, g, dim3(256), 0, stream, src, hi, lo, K, N);
    };
    prep(W_kj,    HKJ, LKJ, 128, 128, 4);
    prep(W_ji,    HJI, LJI, 128, 128, 4);
    prep(W_down,  HDN, LDN, 128, 64,  4);
    prep(W_up,    HUP, LUP, 64,  128, 4);
    prep(Wb,      HWB, LWB, 128, 128, 8);
    prep(Wa,      HWA, LWA, 128, 128, 16);
    prep(W_lin,   HLN, LLN, 128, 128, 4);
    prep(Wo_up,   HOU, LOU, 128, 256, 5);
    prep(Wo_lins, HOL, LOL, 256, 256, 15);

    // ---- build triplet CSR (idx_ji: T entries -> E buckets)
    {
        const int nbT = (E_EDGES + 255) / 256;
        hipMemsetAsync(tcnt, 0, (size_t)E_EDGES * 4, stream);
        hipLaunchKernelGGL(csr_count, dim3((T_TRIP + 255) / 256), dim3(256), 0, stream,
                           idx_ji, tcnt, T_TRIP);
        hipLaunchKernelGGL(scan_block, dim3(nbT), dim3(256), 0, stream, tcnt, tptr, tbsum, E_EDGES);
        hipLaunchKernelGGL(scan_aux, dim3(1), dim3(1024), 0, stream, tbsum, nbT);
        hipLaunchKernelGGL(scan_add, dim3(nbT), dim3(256), 0, stream, tptr, tbsum, E_EDGES);
        hipMemcpyAsync(tcur, tptr, (size_t)E_EDGES * 4, hipMemcpyDeviceToDevice, stream);
        hipLaunchKernelGGL(csr_fill, dim3((T_TRIP + 255) / 256), dim3(256), 0, stream,
                           idx_ji, tcur, tperm, T_TRIP);
    }
    // ---- build node CSR (idx_i: E entries -> N buckets)
    {
        const int nbN = (N_NODES + 255) / 256;
        hipMemsetAsync(ecnt, 0, (size_t)N_NODES * 4, stream);
        hipLaunchKernelGGL(csr_count, dim3((E_EDGES + 255) / 256), dim3(256), 0, stream,
                           idx_i, ecnt, E_EDGES);
        hipLaunchKernelGGL(scan_block, dim3(nbN), dim3(256), 0, stream, ecnt, eptr, ebsum, N_NODES);
        hipLaunchKernelGGL(scan_aux, dim3(1), dim3(1024), 0, stream, ebsum, nbN);
        hipLaunchKernelGGL(scan_add, dim3(nbN), dim3(256), 0, stream, eptr, ebsum, N_NODES);
        hipMemcpyAsync(ecur, eptr, (size_t)N_NODES * 4, hipMemcpyDeviceToDevice, stream);
        hipLaunchKernelGGL(csr_fill, dim3((E_EDGES + 255) / 256), dim3(256), 0, stream,
                           idx_i, ecur, eperm, E_EDGES);
    }
    // ---- one-time permuted sbf basis for all blocks
    hipLaunchKernelGGL(permute_s8, dim3((T_TRIP + 255) / 256), dim3(256), 0, stream,
                       sbf, W_sbf1, idx_kj, tperm, PS8, PKJ, T_TRIP);

    auto gemm = [&](const float* A, const u16* Bh, const u16* Bl, const float* bias,
                    const float* res, const float* r8, const float* Wr2f,
                    float* C, int M, int N, int K, int flags) {
        dim3 g(N / 64, (M + 127) / 128), b(256);
        hipLaunchKernelGGL(mfma_gemm, g, b, 0, stream,
                           A, Bh, Bl, bias, res, r8, Wr2f, C, M, N, K, flags);
    };
    auto fpair = [&](float* X, const u16* W1h, const u16* W1l, const u16* W2h, const u16* W2l,
                     const float* bias1, const float* bias2, int M) {
        hipLaunchKernelGGL(fused_pair, dim3((M + 63) / 64), dim3(256), 0, stream,
                           X, W1h, W1l, W2h, W2l, bias1, bias2, X, M);
    };

    float* P = (float*)d_out;
    hipMemsetAsync(P, 0, (size_t)N_NODES * sizeof(float), stream);

    auto out_block = [&](int ob, const float* xcur) {
        hipLaunchKernelGGL(out_gather, dim3(2048), dim3(256), 0, stream,
                           rbf, Wo_rbf + (size_t)ob * NRAD * H_DIM, xcur,
                           eptr, ecnt, eperm, TN, N_NODES);
        gemm(TN, HOU + (size_t)ob * 32768, LOU + (size_t)ob * 32768,
             bo_up + (size_t)ob * OUT_EMB, nullptr, nullptr, nullptr,
             T1, N_NODES, OUT_EMB, H_DIM, F_BIAS);
        float* src = T1; float* dst = T2;
        for (int l = 0; l < 3; ++l) {
            gemm(src, HOL + (size_t)(ob * 3 + l) * 65536, LOL + (size_t)(ob * 3 + l) * 65536,
                 bo_lins + (size_t)(ob * 3 + l) * OUT_EMB, nullptr, nullptr, nullptr,
                 dst, N_NODES, OUT_EMB, OUT_EMB, F_BIAS | F_SILU);
            float* tmp = src; src = dst; dst = tmp;
        }
        hipLaunchKernelGGL(out_final, dim3((N_NODES * 64 + 255) / 256), dim3(256), 0, stream,
                           src, Wo_out + (size_t)ob * OUT_EMB, P, N_NODES);
    };

    out_block(0, x_in);

    const float* xcur = x_in;
    for (int b = 0; b < NB; ++b) {
        float* xnext = (b % 2 == 0) ? XB : XA;
        hipLaunchKernelGGL(rbf8_kernel, dim3((E_EDGES + 255) / 256), dim3(256), 0, stream,
                           rbf, W_rbf1 + (size_t)b * NRAD * BAS, R8, E_EDGES);
        // x_ji = silu(x @ W_ji + b_ji)
        gemm(xcur, HJI + (size_t)b * 16384, LJI + (size_t)b * 16384, b_ji + (size_t)b * H_DIM,
             nullptr, nullptr, nullptr, E1, E_EDGES, H_DIM, H_DIM, F_BIAS | F_SILU);
        // x_kj_g = silu(x @ W_kj + b_kj) * (rbf8 @ W_rbf2)
        gemm(xcur, HKJ + (size_t)b * 16384, LKJ + (size_t)b * 16384, b_kj + (size_t)b * H_DIM,
             nullptr, R8, W_rbf2 + (size_t)b * BAS * H_DIM,
             E2, E_EDGES, H_DIM, H_DIM, F_BIAS | F_SILU | F_GATE);
        // x_kj_d = silu(x_kj_g @ W_down)
        gemm(E2, HDN + (size_t)b * 8192, LDN + (size_t)b * 8192, nullptr,
             nullptr, nullptr, nullptr, C1, E_EDGES, INT_DIM, H_DIM, F_SILU);
        // triplet aggregation (permuted stream, atomic-free)
        hipLaunchKernelGGL(triplet_gather2, dim3(2048), dim3(256), 0, stream,
                           PS8 + (size_t)b * T_TRIP * BAS, W_sbf2 + (size_t)b * BAS * INT_DIM,
                           C1, PKJ, tptr, tcnt, C2, E_EDGES);
        // h = x_ji + silu(agg @ W_up)
        gemm(C2, HUP + (size_t)b * 8192, LUP + (size_t)b * 8192, nullptr,
             E1, nullptr, nullptr, E1, E_EDGES, H_DIM, INT_DIM, F_SILU | F_RES);
        // before-skip residual layer (fused pair), in-place on E1
        fpair(E1, HWB + (size_t)(b * 2 + 0) * 16384, LWB + (size_t)(b * 2 + 0) * 16384,
              HWB + (size_t)(b * 2 + 1) * 16384, LWB + (size_t)(b * 2 + 1) * 16384,
              bb + (size_t)(b * 2 + 0) * H_DIM, bb + (size_t)(b * 2 + 1) * H_DIM, E_EDGES);
        // skip: x_next = silu(h @ W_lin + b_lin) + x
        gemm(E1, HLN + (size_t)b * 16384, LLN + (size_t)b * 16384, b_lin + (size_t)b * H_DIM,
             xcur, nullptr, nullptr, xnext, E_EDGES, H_DIM, H_DIM, F_BIAS | F_SILU | F_RES);
        // after-skip residual layers (fused pairs), in-place on xnext
        for (int l = 0; l < 2; ++l) {
            fpair(xnext,
                  HWA + (size_t)(b * 4 + 2 * l) * 16384,     LWA + (size_t)(b * 4 + 2 * l) * 16384,
                  HWA + (size_t)(b * 4 + 2 * l + 1) * 16384, LWA + (size_t)(b * 4 + 2 * l + 1) * 16384,
                  ba + (size_t)(b * 4 + 2 * l) * H_DIM, ba + (size_t)(b * 4 + 2 * l + 1) * H_DIM,
                  E_EDGES);
        }
        xcur = xnext;
        out_block(b + 1, xcur);
    }
}

// Round 5
// 4897.660 us; speedup vs baseline: 1.8369x; 1.2047x over previous
//
#include <hip/hip_runtime.h>
#include <hip/hip_bf16.h>

// Problem constants (fixed by the reference)
#define E_EDGES 200000
#define T_TRIP  2000000
#define N_NODES 20000
#define H_DIM   128
#define INT_DIM 64
#define BAS     8
#define OUT_EMB 256
#define NRAD    6
#define SBF_D   42
#define NB      4

// epilogue flags
#define F_BIAS 1
#define F_SILU 2
#define F_RES  4
#define F_GATE 8

typedef __attribute__((ext_vector_type(8))) __bf16 bf16x8;
typedef __attribute__((ext_vector_type(4))) float f32x4;
typedef unsigned short u16;

__device__ __forceinline__ float silu_f(float v) { return v / (1.0f + __expf(-v)); }

__device__ __forceinline__ u16 f2bf(float f) {
    unsigned int u = __float_as_uint(f);
    u += 0x7FFF + ((u >> 16) & 1);   // RNE
    return (u16)(u >> 16);
}
__device__ __forceinline__ float bf2f(u16 h) {
    return __uint_as_float(((unsigned int)h) << 16);
}

// split-bf16 LDS helpers; colsx2 = row stride in bytes (cols*2)
__device__ __forceinline__ void st_split(char* H, char* L, int row, int col, int stride, float v) {
    u16 hh = f2bf(v);
    u16 ll = f2bf(v - bf2f(hh));
    int off = (row * stride + col * 2) ^ ((row & 7) << 4);
    *reinterpret_cast<u16*>(H + off) = hh;
    *reinterpret_cast<u16*>(L + off) = ll;
}
__device__ __forceinline__ float ld_split(const char* H, const char* L, int row, int col, int stride) {
    int off = (row * stride + col * 2) ^ ((row & 7) << 4);
    return bf2f(*reinterpret_cast<const u16*>(H + off))
         + bf2f(*reinterpret_cast<const u16*>(L + off));
}

// GEMM from LDS A [64][128] split-bf16 (stride 256B), weights [N][128] split.
// Wave tile 32(m) x 64(n): acc[2][4]. 3-term split MFMA.
__device__ __forceinline__ void mm128(
    const char* AH, const char* AL, const u16* Bh, const u16* Bl,
    int wm, int wn, int l15, int khalf, f32x4 acc[2][4])
{
    #pragma unroll
    for (int k0 = 0; k0 < 128; k0 += 32) {
        bf16x8 bh[4], bl[4];
        #pragma unroll
        for (int n = 0; n < 4; ++n) {
            size_t bo = (size_t)(wn * 64 + n * 16 + l15) * 128 + k0 + khalf;
            bh[n] = *reinterpret_cast<const bf16x8*>(Bh + bo);
            bl[n] = *reinterpret_cast<const bf16x8*>(Bl + bo);
        }
        #pragma unroll
        for (int m = 0; m < 2; ++m) {
            int row = wm * 32 + m * 16 + l15;
            int off = (row * 256 + (k0 + khalf) * 2) ^ ((row & 7) << 4);
            bf16x8 ah = *reinterpret_cast<const bf16x8*>(AH + off);
            bf16x8 al = *reinterpret_cast<const bf16x8*>(AL + off);
            #pragma unroll
            for (int n = 0; n < 4; ++n) {
                acc[m][n] = __builtin_amdgcn_mfma_f32_16x16x32_bf16(ah, bh[n], acc[m][n], 0, 0, 0);
                acc[m][n] = __builtin_amdgcn_mfma_f32_16x16x32_bf16(al, bh[n], acc[m][n], 0, 0, 0);
                acc[m][n] = __builtin_amdgcn_mfma_f32_16x16x32_bf16(ah, bl[n], acc[m][n], 0, 0, 0);
            }
        }
    }
}

// K=64 variant: LDS A [64][64] split (stride 128B), weights [128][64] split.
__device__ __forceinline__ void mm64(
    const char* AH, const char* AL, const u16* Bh, const u16* Bl,
    int wm, int wn, int l15, int khalf, f32x4 acc[2][4])
{
    #pragma unroll
    for (int k0 = 0; k0 < 64; k0 += 32) {
        bf16x8 bh[4], bl[4];
        #pragma unroll
        for (int n = 0; n < 4; ++n) {
            size_t bo = (size_t)(wn * 64 + n * 16 + l15) * 64 + k0 + khalf;
            bh[n] = *reinterpret_cast<const bf16x8*>(Bh + bo);
            bl[n] = *reinterpret_cast<const bf16x8*>(Bl + bo);
        }
        #pragma unroll
        for (int m = 0; m < 2; ++m) {
            int row = wm * 32 + m * 16 + l15;
            int off = (row * 128 + (k0 + khalf) * 2) ^ ((row & 7) << 4);
            bf16x8 ah = *reinterpret_cast<const bf16x8*>(AH + off);
            bf16x8 al = *reinterpret_cast<const bf16x8*>(AL + off);
            #pragma unroll
            for (int n = 0; n < 4; ++n) {
                acc[m][n] = __builtin_amdgcn_mfma_f32_16x16x32_bf16(ah, bh[n], acc[m][n], 0, 0, 0);
                acc[m][n] = __builtin_amdgcn_mfma_f32_16x16x32_bf16(al, bh[n], acc[m][n], 0, 0, 0);
                acc[m][n] = __builtin_amdgcn_mfma_f32_16x16x32_bf16(ah, bl[n], acc[m][n], 0, 0, 0);
            }
        }
    }
}

// ---------------------------------------------------------------------------
// Weight prep: src [cnt][K][N] f32 row-major -> hi/lo [cnt][N][K] split-bf16
// ---------------------------------------------------------------------------
__global__ __launch_bounds__(256) void wprep(
    const float* __restrict__ src, u16* __restrict__ hi,
    u16* __restrict__ lo, int K, int N)
{
    int e = blockIdx.x * 256 + threadIdx.x;
    int total = K * N;
    if (e >= total) return;
    size_t base = (size_t)blockIdx.y * total;
    float a = src[base + e];
    int k = e / N, n = e - k * N;
    u16 h = f2bf(a);
    u16 l = f2bf(a - bf2f(h));
    hi[base + (size_t)n * K + k] = h;
    lo[base + (size_t)n * K + k] = l;
}

// ---------------------------------------------------------------------------
// Generic split-bf16 MFMA GEMM (used by output blocks)
// ---------------------------------------------------------------------------
__global__ __launch_bounds__(256) void mfma_gemm(
    const float* __restrict__ A,
    const u16* __restrict__ Bhi, const u16* __restrict__ Blo,
    const float* __restrict__ bias, const float* __restrict__ res,
    const float* __restrict__ rbf8v, const float* __restrict__ Wr2,
    float* __restrict__ C, int M, int N, int K, int flags)
{
    __shared__ u16 AsH[128 * 32];
    __shared__ u16 AsL[128 * 32];

    const int tid  = threadIdx.x;
    const int lane = tid & 63;
    const int w    = tid >> 6;
    const int wm   = w >> 1, wn = w & 1;
    const int bm   = blockIdx.y * 128;
    const int bn   = blockIdx.x * 64;
    const int l15  = lane & 15;
    const int khalf = (lane >> 4) * 8;

    const int sr = tid >> 1;
    const int sc = (tid & 1) * 16;
    int grow = bm + sr; if (grow >= M) grow = M - 1;
    const float* gA = &A[(size_t)grow * K + sc];

    int bcol[2];
    #pragma unroll
    for (int n = 0; n < 2; ++n) bcol[n] = bn + wn * 32 + n * 16 + l15;

    f32x4 acc[4][2] = {};

    for (int k0 = 0; k0 < K; k0 += 32) {
        __syncthreads();
        {
            const float* p = gA + k0;
            float4 f0 = *reinterpret_cast<const float4*>(p);
            float4 f1 = *reinterpret_cast<const float4*>(p + 4);
            float4 f2 = *reinterpret_cast<const float4*>(p + 8);
            float4 f3 = *reinterpret_cast<const float4*>(p + 12);
            float vv[16] = {f0.x,f0.y,f0.z,f0.w, f1.x,f1.y,f1.z,f1.w,
                            f2.x,f2.y,f2.z,f2.w, f3.x,f3.y,f3.z,f3.w};
            const int swz = (sr & 7) << 4;
            #pragma unroll
            for (int q = 0; q < 4; ++q) {
                u16 h[4], l[4];
                #pragma unroll
                for (int j = 0; j < 4; ++j) {
                    float a = vv[q * 4 + j];
                    h[j] = f2bf(a);
                    l[j] = f2bf(a - bf2f(h[j]));
                }
                int off = (sr * 64 + (sc / 4 + q) * 8) ^ swz;
                *reinterpret_cast<ushort4*>((char*)AsH + off) = make_ushort4(h[0], h[1], h[2], h[3]);
                *reinterpret_cast<ushort4*>((char*)AsL + off) = make_ushort4(l[0], l[1], l[2], l[3]);
            }
        }
        __syncthreads();

        bf16x8 bh[2], bl[2];
        #pragma unroll
        for (int n = 0; n < 2; ++n) {
            size_t bo = (size_t)bcol[n] * K + k0 + khalf;
            bh[n] = *reinterpret_cast<const bf16x8*>(Bhi + bo);
            bl[n] = *reinterpret_cast<const bf16x8*>(Blo + bo);
        }

        #pragma unroll
        for (int m = 0; m < 4; ++m) {
            int ri  = wm * 64 + m * 16 + l15;
            int off = (ri * 64 + khalf * 2) ^ ((ri & 7) << 4);
            bf16x8 ah = *reinterpret_cast<const bf16x8*>((const char*)AsH + off);
            bf16x8 al = *reinterpret_cast<const bf16x8*>((const char*)AsL + off);
            #pragma unroll
            for (int n = 0; n < 2; ++n) {
                acc[m][n] = __builtin_amdgcn_mfma_f32_16x16x32_bf16(ah, bh[n], acc[m][n], 0, 0, 0);
                acc[m][n] = __builtin_amdgcn_mfma_f32_16x16x32_bf16(al, bh[n], acc[m][n], 0, 0, 0);
                acc[m][n] = __builtin_amdgcn_mfma_f32_16x16x32_bf16(ah, bl[n], acc[m][n], 0, 0, 0);
            }
        }
    }

    const int r4 = (lane >> 4) * 4;
    #pragma unroll
    for (int m = 0; m < 4; ++m) {
        #pragma unroll
        for (int r = 0; r < 4; ++r) {
            int row = bm + wm * 64 + m * 16 + r4 + r;
            if (row >= M) continue;
            #pragma unroll
            for (int n = 0; n < 2; ++n) {
                int col = bn + wn * 32 + n * 16 + l15;
                float v = acc[m][n][r];
                if (flags & F_BIAS) v += bias[col];
                if (flags & F_SILU) v = silu_f(v);
                if (flags & F_GATE) {
                    float g = 0.f;
                    #pragma unroll
                    for (int j = 0; j < 8; ++j)
                        g = fmaf(rbf8v[(size_t)row * 8 + j], Wr2[j * N + col], g);
                    v *= g;
                }
                if (flags & F_RES) v += res[(size_t)row * N + col];
                C[(size_t)row * N + col] = v;
            }
        }
    }
}

// ---------------------------------------------------------------------------
// pre_fuse: per 64-edge tile, stage X once; compute
//   E1 = silu(X@Wji + bji)
//   I  = silu(X@Wkj + bkj) * (R8 @ Wr2)      (kept in LDS)
//   C1 = silu(I@Wdn)                          (N=64)
// ---------------------------------------------------------------------------
__global__ __launch_bounds__(256, 2) void pre_fuse(
    const float* __restrict__ X, const float* __restrict__ R8,
    const u16* __restrict__ Wjih, const u16* __restrict__ Wjil, const float* __restrict__ bji,
    const u16* __restrict__ Wkjh, const u16* __restrict__ Wkjl, const float* __restrict__ bkj,
    const float* __restrict__ Wr2,
    const u16* __restrict__ Wdnh, const u16* __restrict__ Wdnl,
    float* __restrict__ E1, float* __restrict__ C1)
{
    __shared__ u16 XH[64 * 128], XL[64 * 128];
    __shared__ u16 IH[64 * 128], IL[64 * 128];

    const int tid  = threadIdx.x;
    const int lane = tid & 63;
    const int w    = tid >> 6;
    const int wm   = w >> 1, wn = w & 1;
    const int bm   = blockIdx.x * 64;
    const int l15  = lane & 15;
    const int khalf = (lane >> 4) * 8;
    const int r4   = (lane >> 4) * 4;

    // stage X [64][128]
    {
        int r  = tid >> 2;
        int c0 = (tid & 3) * 32;
        const float* p = &X[(size_t)(bm + r) * H_DIM + c0];
        const int swz = (r & 7) << 4;
        #pragma unroll
        for (int q = 0; q < 8; ++q) {
            float4 f = *reinterpret_cast<const float4*>(p + q * 4);
            float vv[4] = {f.x, f.y, f.z, f.w};
            u16 h[4], l[4];
            #pragma unroll
            for (int j = 0; j < 4; ++j) {
                h[j] = f2bf(vv[j]);
                l[j] = f2bf(vv[j] - bf2f(h[j]));
            }
            int off = (r * 256 + c0 * 2 + q * 8) ^ swz;
            *reinterpret_cast<ushort4*>((char*)XH + off) = make_ushort4(h[0], h[1], h[2], h[3]);
            *reinterpret_cast<ushort4*>((char*)XL + off) = make_ushort4(l[0], l[1], l[2], l[3]);
        }
    }
    __syncthreads();

    // JI -> E1
    {
        f32x4 acc[2][4] = {};
        mm128((char*)XH, (char*)XL, Wjih, Wjil, wm, wn, l15, khalf, acc);
        #pragma unroll
        for (int n = 0; n < 4; ++n) {
            int col = wn * 64 + n * 16 + l15;
            float bv = bji[col];
            #pragma unroll
            for (int m = 0; m < 2; ++m)
                #pragma unroll
                for (int r = 0; r < 4; ++r) {
                    int row = wm * 32 + m * 16 + r4 + r;
                    E1[(size_t)(bm + row) * H_DIM + col] = silu_f(acc[m][n][r] + bv);
                }
        }
    }
    // KJ * gate -> I (LDS)
    {
        f32x4 acc[2][4] = {};
        mm128((char*)XH, (char*)XL, Wkjh, Wkjl, wm, wn, l15, khalf, acc);
        #pragma unroll
        for (int n = 0; n < 4; ++n) {
            int col = wn * 64 + n * 16 + l15;
            float bv = bkj[col];
            #pragma unroll
            for (int m = 0; m < 2; ++m)
                #pragma unroll
                for (int r = 0; r < 4; ++r) {
                    int row = wm * 32 + m * 16 + r4 + r;
                    float v = silu_f(acc[m][n][r] + bv);
                    float g = 0.f;
                    #pragma unroll
                    for (int j = 0; j < 8; ++j)
                        g = fmaf(R8[(size_t)(bm + row) * 8 + j], Wr2[j * H_DIM + col], g);
                    st_split((char*)IH, (char*)IL, row, col, 256, v * g);
                }
        }
    }
    __syncthreads();

    // DOWN (N=64) -> C1
    {
        f32x4 acc[2][2] = {};
        #pragma unroll
        for (int k0 = 0; k0 < 128; k0 += 32) {
            bf16x8 bh[2], bl[2];
            #pragma unroll
            for (int n = 0; n < 2; ++n) {
                size_t bo = (size_t)(wn * 32 + n * 16 + l15) * 128 + k0 + khalf;
                bh[n] = *reinterpret_cast<const bf16x8*>(Wdnh + bo);
                bl[n] = *reinterpret_cast<const bf16x8*>(Wdnl + bo);
            }
            #pragma unroll
            for (int m = 0; m < 2; ++m) {
                int row = wm * 32 + m * 16 + l15;
                int off = (row * 256 + (k0 + khalf) * 2) ^ ((row & 7) << 4);
                bf16x8 ah = *reinterpret_cast<const bf16x8*>((const char*)IH + off);
                bf16x8 al = *reinterpret_cast<const bf16x8*>((const char*)IL + off);
                #pragma unroll
                for (int n = 0; n < 2; ++n) {
                    acc[m][n] = __builtin_amdgcn_mfma_f32_16x16x32_bf16(ah, bh[n], acc[m][n], 0, 0, 0);
                    acc[m][n] = __builtin_amdgcn_mfma_f32_16x16x32_bf16(al, bh[n], acc[m][n], 0, 0, 0);
                    acc[m][n] = __builtin_amdgcn_mfma_f32_16x16x32_bf16(ah, bl[n], acc[m][n], 0, 0, 0);
                }
            }
        }
        #pragma unroll
        for (int n = 0; n < 2; ++n) {
            int col = wn * 32 + n * 16 + l15;
            #pragma unroll
            for (int m = 0; m < 2; ++m)
                #pragma unroll
                for (int r = 0; r < 4; ++r) {
                    int row = wm * 32 + m * 16 + r4 + r;
                    C1[(size_t)(bm + row) * INT_DIM + col] = silu_f(acc[m][n][r]);
                }
        }
    }
}

// ---------------------------------------------------------------------------
// post_chain: per 64-edge tile,
//   h  = E1 + silu(AGG@Wup)
//   h  = h + silu(silu(h@Wb0+bb0)@Wb1+bb1)
//   x' = silu(h@Wlin+blin) + X
//   x' = x' + silu(silu(x'@Wa0+ba0)@Wa1+ba1)
//   x' = x' + silu(silu(x'@Wa2+ba2)@Wa3+ba3)  -> OUT
// ---------------------------------------------------------------------------
struct ChainP {
    const u16 *uph, *upl;
    const u16 *b0h, *b0l, *b1h, *b1l;
    const u16 *lnh, *lnl;
    const u16 *a0h, *a0l, *a1h, *a1l, *a2h, *a2l, *a3h, *a3l;
    const float *bb0, *bb1, *blin, *ba0, *ba1, *ba2, *ba3;
};

__global__ __launch_bounds__(256, 2) void post_chain(
    const float* __restrict__ AGG, const float* __restrict__ E1,
    const float* __restrict__ X, ChainP p, float* __restrict__ OUT)
{
    __shared__ u16 GH[64 * 64],  GL[64 * 64];
    __shared__ u16 P0H[64 * 128], P0L[64 * 128];
    __shared__ u16 P1H[64 * 128], P1L[64 * 128];

    const int tid  = threadIdx.x;
    const int lane = tid & 63;
    const int w    = tid >> 6;
    const int wm   = w >> 1, wn = w & 1;
    const int bm   = blockIdx.x * 64;
    const int l15  = lane & 15;
    const int khalf = (lane >> 4) * 8;
    const int r4   = (lane >> 4) * 4;

    // stage AGG [64][64]
    {
        int r  = tid >> 2;
        int c0 = (tid & 3) * 16;
        const float* pg = &AGG[(size_t)(bm + r) * INT_DIM + c0];
        const int swz = (r & 7) << 4;
        #pragma unroll
        for (int q = 0; q < 4; ++q) {
            float4 f = *reinterpret_cast<const float4*>(pg + q * 4);
            float vv[4] = {f.x, f.y, f.z, f.w};
            u16 h[4], l[4];
            #pragma unroll
            for (int j = 0; j < 4; ++j) {
                h[j] = f2bf(vv[j]);
                l[j] = f2bf(vv[j] - bf2f(h[j]));
            }
            int off = (r * 128 + c0 * 2 + q * 8) ^ swz;
            *reinterpret_cast<ushort4*>((char*)GH + off) = make_ushort4(h[0], h[1], h[2], h[3]);
            *reinterpret_cast<ushort4*>((char*)GL + off) = make_ushort4(l[0], l[1], l[2], l[3]);
        }
    }
    __syncthreads();

    f32x4 acc[2][4];

    // S1: UP (K=64), h0 = E1 + silu(acc) -> P0
    #pragma unroll
    for (int m = 0; m < 2; ++m)
        #pragma unroll
        for (int n = 0; n < 4; ++n) acc[m][n] = f32x4{0.f, 0.f, 0.f, 0.f};
    mm64((char*)GH, (char*)GL, p.uph, p.upl, wm, wn, l15, khalf, acc);
    #pragma unroll
    for (int n = 0; n < 4; ++n) {
        int col = wn * 64 + n * 16 + l15;
        #pragma unroll
        for (int m = 0; m < 2; ++m)
            #pragma unroll
            for (int r = 0; r < 4; ++r) {
                int row = wm * 32 + m * 16 + r4 + r;
                float v = E1[(size_t)(bm + row) * H_DIM + col] + silu_f(acc[m][n][r]);
                st_split((char*)P0H, (char*)P0L, row, col, 256, v);
            }
    }
    __syncthreads();

    // macro-ish stages
    #define STAGE_PLAIN(SRC_H, SRC_L, WH, WL, BIAS, DST_H, DST_L)                       \
    {                                                                                   \
        _Pragma("unroll")                                                               \
        for (int m = 0; m < 2; ++m)                                                     \
            _Pragma("unroll")                                                           \
            for (int n = 0; n < 4; ++n) acc[m][n] = f32x4{0.f, 0.f, 0.f, 0.f};          \
        mm128((char*)SRC_H, (char*)SRC_L, WH, WL, wm, wn, l15, khalf, acc);             \
        _Pragma("unroll")                                                               \
        for (int n = 0; n < 4; ++n) {                                                   \
            int col = wn * 64 + n * 16 + l15;                                           \
            float bv = BIAS[col];                                                       \
            _Pragma("unroll")                                                           \
            for (int m = 0; m < 2; ++m)                                                 \
                _Pragma("unroll")                                                       \
                for (int r = 0; r < 4; ++r) {                                           \
                    int row = wm * 32 + m * 16 + r4 + r;                                \
                    st_split((char*)DST_H, (char*)DST_L, row, col, 256,                 \
                             silu_f(acc[m][n][r] + bv));                                \
                }                                                                       \
        }                                                                               \
        __syncthreads();                                                                \
    }

    #define STAGE_RES(SRC_H, SRC_L, WH, WL, BIAS, RES_H, RES_L)                         \
    {                                                                                   \
        _Pragma("unroll")                                                               \
        for (int m = 0; m < 2; ++m)                                                     \
            _Pragma("unroll")                                                           \
            for (int n = 0; n < 4; ++n) acc[m][n] = f32x4{0.f, 0.f, 0.f, 0.f};          \
        mm128((char*)SRC_H, (char*)SRC_L, WH, WL, wm, wn, l15, khalf, acc);             \
        _Pragma("unroll")                                                               \
        for (int n = 0; n < 4; ++n) {                                                   \
            int col = wn * 64 + n * 16 + l15;                                           \
            float bv = BIAS[col];                                                       \
            _Pragma("unroll")                                                           \
            for (int m = 0; m < 2; ++m)                                                 \
                _Pragma("unroll")                                                       \
                for (int r = 0; r < 4; ++r) {                                           \
                    int row = wm * 32 + m * 16 + r4 + r;                                \
                    float v = ld_split((char*)RES_H, (char*)RES_L, row, col, 256)       \
                            + silu_f(acc[m][n][r] + bv);                                \
                    st_split((char*)RES_H, (char*)RES_L, row, col, 256, v);             \
                }                                                                       \
        }                                                                               \
        __syncthreads();                                                                \
    }

    // S2: P1 = silu(P0@Wb0+bb0)
    STAGE_PLAIN(P0H, P0L, p.b0h, p.b0l, p.bb0, P1H, P1L)
    // S3: P0 += silu(P1@Wb1+bb1)   (h1 in P0)
    STAGE_RES(P1H, P1L, p.b1h, p.b1l, p.bb1, P0H, P0L)

    // S4: x1 = silu(P0@Wlin+blin) + X -> P1
    {
        #pragma unroll
        for (int m = 0; m < 2; ++m)
            #pragma unroll
            for (int n = 0; n < 4; ++n) acc[m][n] = f32x4{0.f, 0.f, 0.f, 0.f};
        mm128((char*)P0H, (char*)P0L, p.lnh, p.lnl, wm, wn, l15, khalf, acc);
        #pragma unroll
        for (int n = 0; n < 4; ++n) {
            int col = wn * 64 + n * 16 + l15;
            float bv = p.blin[col];
            #pragma unroll
            for (int m = 0; m < 2; ++m)
                #pragma unroll
                for (int r = 0; r < 4; ++r) {
                    int row = wm * 32 + m * 16 + r4 + r;
                    float v = silu_f(acc[m][n][r] + bv) + X[(size_t)(bm + row) * H_DIM + col];
                    st_split((char*)P1H, (char*)P1L, row, col, 256, v);
                }
        }
        __syncthreads();
    }

    // S5: P0 = silu(P1@Wa0+ba0)
    STAGE_PLAIN(P1H, P1L, p.a0h, p.a0l, p.ba0, P0H, P0L)
    // S6: P1 += silu(P0@Wa1+ba1)   (x2 in P1)
    STAGE_RES(P0H, P0L, p.a1h, p.a1l, p.ba1, P1H, P1L)
    // S7: P0 = silu(P1@Wa2+ba2)
    STAGE_PLAIN(P1H, P1L, p.a2h, p.a2l, p.ba2, P0H, P0L)

    // S8: OUT = P1 + silu(P0@Wa3+ba3)
    {
        #pragma unroll
        for (int m = 0; m < 2; ++m)
            #pragma unroll
            for (int n = 0; n < 4; ++n) acc[m][n] = f32x4{0.f, 0.f, 0.f, 0.f};
        mm128((char*)P0H, (char*)P0L, p.a3h, p.a3l, wm, wn, l15, khalf, acc);
        #pragma unroll
        for (int n = 0; n < 4; ++n) {
            int col = wn * 64 + n * 16 + l15;
            float bv = p.ba3[col];
            #pragma unroll
            for (int m = 0; m < 2; ++m)
                #pragma unroll
                for (int r = 0; r < 4; ++r) {
                    int row = wm * 32 + m * 16 + r4 + r;
                    float v = ld_split((char*)P1H, (char*)P1L, row, col, 256)
                            + silu_f(acc[m][n][r] + bv);
                    OUT[(size_t)(bm + row) * H_DIM + col] = v;
                }
        }
    }
    #undef STAGE_PLAIN
    #undef STAGE_RES
}

// rbf8[e][j] = rbf[e] @ W_rbf1[b]   [E,8]
__global__ __launch_bounds__(256) void rbf8_kernel(
    const float* __restrict__ rbf, const float* __restrict__ W1,
    float* __restrict__ r8, int Ecount)
{
    int e = blockIdx.x * blockDim.x + threadIdx.x;
    if (e >= Ecount) return;
    float rv[NRAD];
    #pragma unroll
    for (int k = 0; k < NRAD; ++k) rv[k] = rbf[(size_t)e * NRAD + k];
    float acc[BAS] = {};
    #pragma unroll
    for (int k = 0; k < NRAD; ++k)
        #pragma unroll
        for (int j = 0; j < BAS; ++j)
            acc[j] = fmaf(rv[k], W1[k * BAS + j], acc[j]);
    float4* o = reinterpret_cast<float4*>(&r8[(size_t)e * BAS]);
    o[0] = make_float4(acc[0], acc[1], acc[2], acc[3]);
    o[1] = make_float4(acc[4], acc[5], acc[6], acc[7]);
}

// ---------------------------------------------------------------------------
// CSR build kernels
// ---------------------------------------------------------------------------
__global__ __launch_bounds__(256) void csr_count(
    const int* __restrict__ idx, int* __restrict__ cnt, int n)
{
    int i = blockIdx.x * 256 + threadIdx.x;
    if (i < n) atomicAdd(&cnt[idx[i]], 1);
}

__global__ __launch_bounds__(256) void scan_block(
    const int* __restrict__ cnt, int* __restrict__ ptr, int* __restrict__ bsum, int n)
{
    __shared__ int s[256];
    int i = blockIdx.x * 256 + threadIdx.x;
    int v = (i < n) ? cnt[i] : 0;
    s[threadIdx.x] = v;
    __syncthreads();
    #pragma unroll
    for (int off = 1; off < 256; off <<= 1) {
        int t = (threadIdx.x >= off) ? s[threadIdx.x - off] : 0;
        __syncthreads();
        s[threadIdx.x] += t;
        __syncthreads();
    }
    if (i < n) ptr[i] = s[threadIdx.x] - v;   // exclusive
    if (threadIdx.x == 255) bsum[blockIdx.x] = s[255];
}

__global__ __launch_bounds__(1024) void scan_aux(int* __restrict__ bsum, int nb)
{
    __shared__ int s[1024];
    int v = (threadIdx.x < nb) ? bsum[threadIdx.x] : 0;
    s[threadIdx.x] = v;
    __syncthreads();
    #pragma unroll
    for (int off = 1; off < 1024; off <<= 1) {
        int t = (threadIdx.x >= off) ? s[threadIdx.x - off] : 0;
        __syncthreads();
        s[threadIdx.x] += t;
        __syncthreads();
    }
    if (threadIdx.x < nb) bsum[threadIdx.x] = s[threadIdx.x] - v;
}

__global__ __launch_bounds__(256) void scan_add(
    int* __restrict__ ptr, const int* __restrict__ bsum, int n)
{
    int i = blockIdx.x * 256 + threadIdx.x;
    if (i < n) ptr[i] += bsum[blockIdx.x];
}

__global__ __launch_bounds__(256) void csr_fill(
    const int* __restrict__ idx, int* __restrict__ cursor,
    int* __restrict__ perm, int n)
{
    int i = blockIdx.x * 256 + threadIdx.x;
    if (i >= n) return;
    int pos = atomicAdd(&cursor[idx[i]], 1);
    perm[pos] = i;
}

// ---------------------------------------------------------------------------
// One-time: permuted sbf basis for ALL blocks + permuted idx_kj.
// ---------------------------------------------------------------------------
__global__ __launch_bounds__(256) void permute_s8(
    const float* __restrict__ sbf, const float* __restrict__ W1all,
    const int* __restrict__ idx_kj, const int* __restrict__ tperm,
    u16* __restrict__ ps8, int* __restrict__ pkj, int Tcount)
{
    __shared__ float Ws[NB * SBF_D * BAS];
    for (int i = threadIdx.x; i < NB * SBF_D * BAS; i += 256) Ws[i] = W1all[i];
    __syncthreads();
    int i = blockIdx.x * 256 + threadIdx.x;
    if (i >= Tcount) return;
    int t = tperm[i];
    pkj[i] = idx_kj[t];
    float s[SBF_D];
    {
        const float2* p2 = reinterpret_cast<const float2*>(&sbf[(size_t)t * SBF_D]);
        #pragma unroll
        for (int k = 0; k < SBF_D / 2; ++k) {
            float2 v = p2[k];
            s[2 * k] = v.x; s[2 * k + 1] = v.y;
        }
    }
    #pragma unroll
    for (int b = 0; b < NB; ++b) {
        const float* Wb_ = &Ws[b * SBF_D * BAS];
        float acc[BAS] = {};
        for (int k = 0; k < SBF_D; ++k) {
            float sv = s[k];
            #pragma unroll
            for (int j = 0; j < BAS; ++j)
                acc[j] = fmaf(sv, Wb_[k * BAS + j], acc[j]);
        }
        ushort4 o0 = make_ushort4(f2bf(acc[0]), f2bf(acc[1]), f2bf(acc[2]), f2bf(acc[3]));
        ushort4 o1 = make_ushort4(f2bf(acc[4]), f2bf(acc[5]), f2bf(acc[6]), f2bf(acc[7]));
        u16* op = &ps8[((size_t)b * Tcount + i) * BAS];
        *reinterpret_cast<ushort4*>(op) = o0;
        *reinterpret_cast<ushort4*>(op + 4) = o1;
    }
}

// ---------------------------------------------------------------------------
// Triplet aggregation, permuted sequential stream
// ---------------------------------------------------------------------------
__device__ __forceinline__ float dot8_bf(uint4 r, const float* w2) {
    float s;
    s  = bf2f((u16)(r.x)) * w2[0] + bf2f((u16)(r.x >> 16)) * w2[1];
    s += bf2f((u16)(r.y)) * w2[2] + bf2f((u16)(r.y >> 16)) * w2[3];
    s += bf2f((u16)(r.z)) * w2[4] + bf2f((u16)(r.z >> 16)) * w2[5];
    s += bf2f((u16)(r.w)) * w2[6] + bf2f((u16)(r.w >> 16)) * w2[7];
    return s;
}

__global__ __launch_bounds__(256) void triplet_gather2(
    const u16* __restrict__ ps8b, const float* __restrict__ Wsb2,
    const float* __restrict__ xkj, const int* __restrict__ pkj,
    const int* __restrict__ tptr, const int* __restrict__ tcnt,
    float* __restrict__ agg, int Ecount)
{
    const int lane = threadIdx.x & 63;
    int wid = (blockIdx.x * blockDim.x + threadIdx.x) >> 6;
    const int nw = (gridDim.x * blockDim.x) >> 6;
    float w2[BAS];
    #pragma unroll
    for (int j = 0; j < BAS; ++j) w2[j] = Wsb2[j * INT_DIM + lane];

    for (int e = wid; e < Ecount; e += nw) {
        int start = tptr[e];
        int end   = start + tcnt[e];
        float acc0 = 0.f, acc1 = 0.f;
        int i = start;
        for (; i + 1 < end; i += 2) {
            uint4 ra = *reinterpret_cast<const uint4*>(&ps8b[(size_t)i * BAS]);
            uint4 rb = *reinterpret_cast<const uint4*>(&ps8b[(size_t)(i + 1) * BAS]);
            int e0 = pkj[i], e1 = pkj[i + 1];
            float s0 = dot8_bf(ra, w2);
            float s1 = dot8_bf(rb, w2);
            acc0 = fmaf(xkj[(size_t)e0 * INT_DIM + lane], s0, acc0);
            acc1 = fmaf(xkj[(size_t)e1 * INT_DIM + lane], s1, acc1);
        }
        if (i < end) {
            uint4 ra = *reinterpret_cast<const uint4*>(&ps8b[(size_t)i * BAS]);
            int e0 = pkj[i];
            acc0 = fmaf(xkj[(size_t)e0 * INT_DIM + lane], dot8_bf(ra, w2), acc0);
        }
        agg[(size_t)e * INT_DIM + lane] = acc0 + acc1;
    }
}

// ---------------------------------------------------------------------------
// Output-block node gather
// ---------------------------------------------------------------------------
__global__ __launch_bounds__(256) void out_gather(
    const float* __restrict__ rbf, const float* __restrict__ Wor,
    const float* __restrict__ x,
    const int* __restrict__ eptr, const int* __restrict__ ecnt,
    const int* __restrict__ eperm, float* __restrict__ tN, int Nn)
{
    const int lane = threadIdx.x & 63;
    int wid = (blockIdx.x * blockDim.x + threadIdx.x) >> 6;
    const int nw = (gridDim.x * blockDim.x) >> 6;
    float wr0[NRAD], wr1[NRAD];
    #pragma unroll
    for (int k = 0; k < NRAD; ++k) {
        wr0[k] = Wor[k * H_DIM + lane];
        wr1[k] = Wor[k * H_DIM + lane + 64];
    }
    for (int n = wid; n < Nn; n += nw) {
        int start = eptr[n];
        int end   = start + ecnt[n];
        float a0 = 0.f, a1 = 0.f;
        for (int i = start; i < end; ++i) {
            int e = eperm[i];
            const float2* rp = reinterpret_cast<const float2*>(&rbf[(size_t)e * NRAD]);
            float2 r0 = rp[0], r1 = rp[1], r2 = rp[2];
            float rA = r0.x*wr0[0] + r0.y*wr0[1] + r1.x*wr0[2]
                     + r1.y*wr0[3] + r2.x*wr0[4] + r2.y*wr0[5];
            float rB = r0.x*wr1[0] + r0.y*wr1[1] + r1.x*wr1[2]
                     + r1.y*wr1[3] + r2.x*wr1[4] + r2.y*wr1[5];
            a0 = fmaf(rA, x[(size_t)e * H_DIM + lane], a0);
            a1 = fmaf(rB, x[(size_t)e * H_DIM + lane + 64], a1);
        }
        tN[(size_t)n * H_DIM + lane] = a0;
        tN[(size_t)n * H_DIM + lane + 64] = a1;
    }
}

// P[n] += dot(Tb[n][:256], Wo[:256]) — one wave per node
__global__ __launch_bounds__(256) void out_final(
    const float* __restrict__ Tb, const float* __restrict__ Wo,
    float* __restrict__ P, int Nn)
{
    const int lane = threadIdx.x & 63;
    int node = (blockIdx.x * blockDim.x + threadIdx.x) >> 6;
    if (node >= Nn) return;
    float s = 0.f;
    #pragma unroll
    for (int i = 0; i < 4; ++i) {
        int c = lane + i * 64;
        s = fmaf(Tb[(size_t)node * OUT_EMB + c], Wo[c], s);
    }
    #pragma unroll
    for (int o = 32; o > 0; o >>= 1) s += __shfl_xor(s, o);
    if (lane == 0) P[node] += s;
}

// ---------------------------------------------------------------------------
extern "C" void kernel_launch(void* const* d_in, const int* in_sizes, int n_in,
                              void* d_out, int out_size, void* d_ws, size_t ws_size,
                              hipStream_t stream)
{
    const float* x_in    = (const float*)d_in[0];
    const float* rbf     = (const float*)d_in[1];
    const float* sbf     = (const float*)d_in[2];
    const float* W_rbf1  = (const float*)d_in[3];
    const float* W_rbf2  = (const float*)d_in[4];
    const float* W_sbf1  = (const float*)d_in[5];
    const float* W_sbf2  = (const float*)d_in[6];
    const float* W_kj    = (const float*)d_in[7];
    const float* b_kj    = (const float*)d_in[8];
    const float* W_ji    = (const float*)d_in[9];
    const float* b_ji    = (const float*)d_in[10];
    const float* W_down  = (const float*)d_in[11];
    const float* W_up    = (const float*)d_in[12];
    const float* Wb      = (const float*)d_in[13];
    const float* bb      = (const float*)d_in[14];
    const float* Wa      = (const float*)d_in[15];
    const float* ba      = (const float*)d_in[16];
    const float* W_lin   = (const float*)d_in[17];
    const float* b_lin   = (const float*)d_in[18];
    const float* Wo_rbf  = (const float*)d_in[19];
    const float* Wo_up   = (const float*)d_in[20];
    const float* bo_up   = (const float*)d_in[21];
    const float* Wo_lins = (const float*)d_in[22];
    const float* bo_lins = (const float*)d_in[23];
    const float* Wo_out  = (const float*)d_in[24];
    const int*   idx_kj  = (const int*)d_in[25];
    const int*   idx_ji  = (const int*)d_in[26];
    const int*   idx_i   = (const int*)d_in[27];

    // workspace carve-up
    char* ws = (char*)d_ws;
    size_t off = 0;
    auto alloc = [&](size_t bytes) -> void* {
        void* p = (void*)(ws + off);
        off += (bytes + 255) & ~(size_t)255;
        return p;
    };
    float* XA = (float*)alloc((size_t)E_EDGES * H_DIM * 4);
    float* XB = (float*)alloc((size_t)E_EDGES * H_DIM * 4);
    float* E1 = (float*)alloc((size_t)E_EDGES * H_DIM * 4);
    float* C1 = (float*)alloc((size_t)E_EDGES * INT_DIM * 4);
    float* C2 = (float*)alloc((size_t)E_EDGES * INT_DIM * 4);
    float* R8 = (float*)alloc((size_t)E_EDGES * BAS * 4);
    float* TN = (float*)alloc((size_t)N_NODES * H_DIM * 4);
    float* T1 = (float*)alloc((size_t)N_NODES * OUT_EMB * 4);
    float* T2 = (float*)alloc((size_t)N_NODES * OUT_EMB * 4);
    // split-bf16 transposed weights
    u16* HKJ = (u16*)alloc(4  * 16384 * 2); u16* LKJ = (u16*)alloc(4  * 16384 * 2);
    u16* HJI = (u16*)alloc(4  * 16384 * 2); u16* LJI = (u16*)alloc(4  * 16384 * 2);
    u16* HDN = (u16*)alloc(4  * 8192  * 2); u16* LDN = (u16*)alloc(4  * 8192  * 2);
    u16* HUP = (u16*)alloc(4  * 8192  * 2); u16* LUP = (u16*)alloc(4  * 8192  * 2);
    u16* HWB = (u16*)alloc(8  * 16384 * 2); u16* LWB = (u16*)alloc(8  * 16384 * 2);
    u16* HWA = (u16*)alloc(16 * 16384 * 2); u16* LWA = (u16*)alloc(16 * 16384 * 2);
    u16* HLN = (u16*)alloc(4  * 16384 * 2); u16* LLN = (u16*)alloc(4  * 16384 * 2);
    u16* HOU = (u16*)alloc(5  * 32768 * 2); u16* LOU = (u16*)alloc(5  * 32768 * 2);
    u16* HOL = (u16*)alloc(15 * 65536 * 2); u16* LOL = (u16*)alloc(15 * 65536 * 2);
    // CSR structures
    int* tcnt  = (int*)alloc((size_t)E_EDGES * 4);
    int* tptr  = (int*)alloc((size_t)E_EDGES * 4);
    int* tcur  = (int*)alloc((size_t)E_EDGES * 4);
    int* tperm = (int*)alloc((size_t)T_TRIP * 4);
    int* tbsum = (int*)alloc(1024 * 4);
    int* ecnt  = (int*)alloc((size_t)N_NODES * 4);
    int* eptr  = (int*)alloc((size_t)N_NODES * 4);
    int* ecur  = (int*)alloc((size_t)N_NODES * 4);
    int* eperm = (int*)alloc((size_t)E_EDGES * 4);
    int* ebsum = (int*)alloc(1024 * 4);
    // permuted triplet stream
    u16* PS8 = (u16*)alloc((size_t)NB * T_TRIP * BAS * 2);
    int* PKJ = (int*)alloc((size_t)T_TRIP * 4);
    (void)ws_size;

    auto prep = [&](const float* src, u16* hi, u16* lo, int K, int N, int cnt) {
        dim3 g((K * N + 255) / 256, cnt);
        hipLaunchKernelGGL(wprep, g, dim3(256), 0, stream, src, hi, lo, K, N);
    };
    prep(W_kj,    HKJ, LKJ, 128, 128, 4);
    prep(W_ji,    HJI, LJI, 128, 128, 4);
    prep(W_down,  HDN, LDN, 128, 64,  4);
    prep(W_up,    HUP, LUP, 64,  128, 4);
    prep(Wb,      HWB, LWB, 128, 128, 8);
    prep(Wa,      HWA, LWA, 128, 128, 16);
    prep(W_lin,   HLN, LLN, 128, 128, 4);
    prep(Wo_up,   HOU, LOU, 128, 256, 5);
    prep(Wo_lins, HOL, LOL, 256, 256, 15);

    // ---- build triplet CSR (idx_ji: T entries -> E buckets)
    {
        const int nbT = (E_EDGES + 255) / 256;
        hipMemsetAsync(tcnt, 0, (size_t)E_EDGES * 4, stream);
        hipLaunchKernelGGL(csr_count, dim3((T_TRIP + 255) / 256), dim3(256), 0, stream,
                           idx_ji, tcnt, T_TRIP);
        hipLaunchKernelGGL(scan_block, dim3(nbT), dim3(256), 0, stream, tcnt, tptr, tbsum, E_EDGES);
        hipLaunchKernelGGL(scan_aux, dim3(1), dim3(1024), 0, stream, tbsum, nbT);
        hipLaunchKernelGGL(scan_add, dim3(nbT), dim3(256), 0, stream, tptr, tbsum, E_EDGES);
        hipMemcpyAsync(tcur, tptr, (size_t)E_EDGES * 4, hipMemcpyDeviceToDevice, stream);
        hipLaunchKernelGGL(csr_fill, dim3((T_TRIP + 255) / 256), dim3(256), 0, stream,
                           idx_ji, tcur, tperm, T_TRIP);
    }
    // ---- build node CSR (idx_i: E entries -> N buckets)
    {
        const int nbN = (N_NODES + 255) / 256;
        hipMemsetAsync(ecnt, 0, (size_t)N_NODES * 4, stream);
        hipLaunchKernelGGL(csr_count, dim3((E_EDGES + 255) / 256), dim3(256), 0, stream,
                           idx_i, ecnt, E_EDGES);
        hipLaunchKernelGGL(scan_block, dim3(nbN), dim3(256), 0, stream, ecnt, eptr, ebsum, N_NODES);
        hipLaunchKernelGGL(scan_aux, dim3(1), dim3(1024), 0, stream, ebsum, nbN);
        hipLaunchKernelGGL(scan_add, dim3(nbN), dim3(256), 0, stream, eptr, ebsum, N_NODES);
        hipMemcpyAsync(ecur, eptr, (size_t)N_NODES * 4, hipMemcpyDeviceToDevice, stream);
        hipLaunchKernelGGL(csr_fill, dim3((E_EDGES + 255) / 256), dim3(256), 0, stream,
                           idx_i, ecur, eperm, E_EDGES);
    }
    // ---- one-time permuted sbf basis for all blocks
    hipLaunchKernelGGL(permute_s8, dim3((T_TRIP + 255) / 256), dim3(256), 0, stream,
                       sbf, W_sbf1, idx_kj, tperm, PS8, PKJ, T_TRIP);

    auto gemm = [&](const float* A, const u16* Bh, const u16* Bl, const float* bias,
                    const float* res, const float* r8, const float* Wr2f,
                    float* C, int M, int N, int K, int flags) {
        dim3 g(N / 64, (M + 127) / 128), b(256);
        hipLaunchKernelGGL(mfma_gemm, g, b, 0, stream,
                           A, Bh, Bl, bias, res, r8, Wr2f, C, M, N, K, flags);
    };

    float* P = (float*)d_out;
    hipMemsetAsync(P, 0, (size_t)N_NODES * sizeof(float), stream);

    auto out_block = [&](int ob, const float* xcur) {
        hipLaunchKernelGGL(out_gather, dim3(2048), dim3(256), 0, stream,
                           rbf, Wo_rbf + (size_t)ob * NRAD * H_DIM, xcur,
                           eptr, ecnt, eperm, TN, N_NODES);
        gemm(TN, HOU + (size_t)ob * 32768, LOU + (size_t)ob * 32768,
             bo_up + (size_t)ob * OUT_EMB, nullptr, nullptr, nullptr,
             T1, N_NODES, OUT_EMB, H_DIM, F_BIAS);
        float* src = T1; float* dst = T2;
        for (int l = 0; l < 3; ++l) {
            gemm(src, HOL + (size_t)(ob * 3 + l) * 65536, LOL + (size_t)(ob * 3 + l) * 65536,
                 bo_lins + (size_t)(ob * 3 + l) * OUT_EMB, nullptr, nullptr, nullptr,
                 dst, N_NODES, OUT_EMB, OUT_EMB, F_BIAS | F_SILU);
            float* tmp = src; src = dst; dst = tmp;
        }
        hipLaunchKernelGGL(out_final, dim3((N_NODES * 64 + 255) / 256), dim3(256), 0, stream,
                           src, Wo_out + (size_t)ob * OUT_EMB, P, N_NODES);
    };

    out_block(0, x_in);

    const float* xcur = x_in;
    const int EB = E_EDGES / 64;  // 3125
    for (int b = 0; b < NB; ++b) {
        float* xnext = (b % 2 == 0) ? XB : XA;
        hipLaunchKernelGGL(rbf8_kernel, dim3((E_EDGES + 255) / 256), dim3(256), 0, stream,
                           rbf, W_rbf1 + (size_t)b * NRAD * BAS, R8, E_EDGES);
        // fused: E1 = silu(x@Wji+bji); C1 = silu((silu(x@Wkj+bkj)*gate)@Wdn)
        hipLaunchKernelGGL(pre_fuse, dim3(EB), dim3(256), 0, stream,
                           xcur, R8,
                           HJI + (size_t)b * 16384, LJI + (size_t)b * 16384, b_ji + (size_t)b * H_DIM,
                           HKJ + (size_t)b * 16384, LKJ + (size_t)b * 16384, b_kj + (size_t)b * H_DIM,
                           W_rbf2 + (size_t)b * BAS * H_DIM,
                           HDN + (size_t)b * 8192, LDN + (size_t)b * 8192,
                           E1, C1);
        // triplet aggregation (permuted stream, atomic-free)
        hipLaunchKernelGGL(triplet_gather2, dim3(2048), dim3(256), 0, stream,
                           PS8 + (size_t)b * T_TRIP * BAS, W_sbf2 + (size_t)b * BAS * INT_DIM,
                           C1, PKJ, tptr, tcnt, C2, E_EDGES);
        // fused chain: UP + pair(Wb) + LIN + pair(Wa0/1) + pair(Wa2/3)
        ChainP cp;
        cp.uph = HUP + (size_t)b * 8192;  cp.upl = LUP + (size_t)b * 8192;
        cp.b0h = HWB + (size_t)(b * 2 + 0) * 16384; cp.b0l = LWB + (size_t)(b * 2 + 0) * 16384;
        cp.b1h = HWB + (size_t)(b * 2 + 1) * 16384; cp.b1l = LWB + (size_t)(b * 2 + 1) * 16384;
        cp.lnh = HLN + (size_t)b * 16384; cp.lnl = LLN + (size_t)b * 16384;
        cp.a0h = HWA + (size_t)(b * 4 + 0) * 16384; cp.a0l = LWA + (size_t)(b * 4 + 0) * 16384;
        cp.a1h = HWA + (size_t)(b * 4 + 1) * 16384; cp.a1l = LWA + (size_t)(b * 4 + 1) * 16384;
        cp.a2h = HWA + (size_t)(b * 4 + 2) * 16384; cp.a2l = LWA + (size_t)(b * 4 + 2) * 16384;
        cp.a3h = HWA + (size_t)(b * 4 + 3) * 16384; cp.a3l = LWA + (size_t)(b * 4 + 3) * 16384;
        cp.bb0 = bb + (size_t)(b * 2 + 0) * H_DIM;
        cp.bb1 = bb + (size_t)(b * 2 + 1) * H_DIM;
        cp.blin = b_lin + (size_t)b * H_DIM;
        cp.ba0 = ba + (size_t)(b * 4 + 0) * H_DIM;
        cp.ba1 = ba + (size_t)(b * 4 + 1) * H_DIM;
        cp.ba2 = ba + (size_t)(b * 4 + 2) * H_DIM;
        cp.ba3 = ba + (size_t)(b * 4 + 3) * H_DIM;
        hipLaunchKernelGGL(post_chain, dim3(EB), dim3(256), 0, stream,
                           C2, E1, xcur, cp, xnext);
        xcur = xnext;
        out_block(b + 1, xcur);
    }
}